// Round 7
// baseline (552.570 us; speedup 1.0000x reference)
//
#include <hip/hip_runtime.h>
#include <hip/hip_bf16.h>
#include <cstddef>

#define N_NODES 65536
#define N_EDGES 524288
#define S_GRAPH 256
#define BN_EPS 1e-5f
#define THRE 0.7f

typedef __hip_bfloat16 bf16;
typedef unsigned int uint32;
typedef unsigned char uchar;
typedef unsigned short ushort16;
typedef __attribute__((ext_vector_type(8))) short short8;
typedef __attribute__((ext_vector_type(4))) float f32x4;

__device__ __forceinline__ float blo(uint32 u) { return __uint_as_float(u << 16); }
__device__ __forceinline__ float bhi(uint32 u) { return __uint_as_float(u & 0xffff0000u); }

__device__ __forceinline__ uint32 packbf(float a, float b)
{
    bf16 ha = __float2bfloat16(a), hb = __float2bfloat16(b);
    unsigned short ua, ub;
    __builtin_memcpy(&ua, &ha, 2); __builtin_memcpy(&ub, &hb, 2);
    return (uint32)ua | ((uint32)ub << 16);
}

// fast tanh: 1 - 2/(e^{2x}+1); |err| ~1e-6, far below bf16 rounding (2^-9)
__device__ __forceinline__ float ftanh(float x)
{
    float e = __builtin_amdgcn_exp2f(x * 2.8853900817779268f);  // 2*log2(e)
    return 1.0f - 2.0f * __builtin_amdgcn_rcpf(e + 1.0f);
}

// device-scope sense-reversal grid barrier (all nblk blocks must call).
// CHEAP-FENCE: one release fence (L2 wb) before arrive, one acquire fence
// (L2 inv) after the generation flips; relaxed polls (verified r5/r6 —
// per-poll acquire destroyed L2: 94MB refetch). Co-residency by capacity.
__device__ __forceinline__ void gbar(int* bar, int nblk)
{
    __syncthreads();
    if (threadIdx.x == 0) {
        __builtin_amdgcn_fence(__ATOMIC_RELEASE, "agent");   // wb dirty L2 once
        int gen = __hip_atomic_load(bar + 1, __ATOMIC_RELAXED, __HIP_MEMORY_SCOPE_AGENT);
        if (__hip_atomic_fetch_add(bar, 1, __ATOMIC_RELAXED, __HIP_MEMORY_SCOPE_AGENT) == nblk - 1) {
            __hip_atomic_store(bar, 0, __ATOMIC_RELAXED, __HIP_MEMORY_SCOPE_AGENT);
            __hip_atomic_fetch_add(bar + 1, 1, __ATOMIC_RELAXED, __HIP_MEMORY_SCOPE_AGENT);
        } else {
            while (__hip_atomic_load(bar + 1, __ATOMIC_RELAXED, __HIP_MEMORY_SCOPE_AGENT) == gen)
                __builtin_amdgcn_s_sleep(8);
        }
        __builtin_amdgcn_fence(__ATOMIC_ACQUIRE, "agent");   // inv stale L2 once
    }
    __syncthreads();
}

// ---------------------------------------------------------------------------
// FRONT kernel: 1057 blocks x 256, 3 grid barriers. 29.7KB LDS -> 5 blk/CU
// (1280 co-resident >= 1057); __launch_bounds__(256,5) caps VGPR at 102.
//  P1: [0..511] bin hist (bin=dst>>8) -> blkhist | [512..1023] node MLP +
//      BN1 stats | [1024..1055] fcol | [1056] W1->bf16
//  P2: per-bin scan of 512 block partials -> blkoff, binsz     [b<256]
//  P3: scatter edges into bin regions (local binsz scan)       [b<512]
//  P4: per-bin CSR build -> dinv, rowp, cnts, epk              [b<256]
// ---------------------------------------------------------------------------
__global__ __launch_bounds__(256, 5) void k_front(
    const float* __restrict__ x, const float* __restrict__ wv,
    const float* __restrict__ bv, const float* __restrict__ wc,
    const float* __restrict__ bc, const int* __restrict__ nconp,
    uint32* __restrict__ h0u, float* __restrict__ stats,
    const int* __restrict__ src, const int* __restrict__ dst,
    const float* __restrict__ ew, uint32* __restrict__ blkhist,
    uint32* __restrict__ blkoff, uint32* __restrict__ binsz,
    const float* __restrict__ scen, float* __restrict__ fcol,
    const float* __restrict__ w1f, uint32* __restrict__ w1bk,
    float* __restrict__ dinv, int* __restrict__ rowp, int* __restrict__ cnts,
    uint2* __restrict__ ebin, int2* __restrict__ epk, int* __restrict__ bar)
{
    __shared__ __align__(16) uchar smem[29696];
    int t = threadIdx.x;
    int b = blockIdx.x;

    // ================= P1 =================
    if (b < 512) {                                // ---- bin histogram ----
        uint32* bh = (uint32*)smem;
        bh[t] = 0;
        __syncthreads();
        int e0 = b * 1024 + t * 4;
        int4 d4 = *(const int4*)(dst + e0);
        atomicAdd(&bh[d4.x >> 8], 1u);
        atomicAdd(&bh[d4.y >> 8], 1u);
        atomicAdd(&bh[d4.z >> 8], 1u);
        atomicAdd(&bh[d4.w >> 8], 1u);
        __syncthreads();
        blkhist[b * 256 + t] = bh[t];
    } else if (b < 1024) {                        // ---- node MLP ----
        float* xs = (float*)smem;                 // 768 floats
        float* sh = (float*)(smem + 3072);        // 256 floats
        int n0 = (b - 512) * 128;
        if (t < 192) ((float4*)xs)[t] = ((const float4*)(x + (size_t)n0 * 6))[t];
        __syncthreads();

        int nc = *nconp;
        int lane = t & 63, wave = t >> 6;
        int j0 = 2 * lane;
        const float2* wv2 = (const float2*)wv;
        float2 wa0 = wv2[j0 * 3], wa1 = wv2[j0 * 3 + 1], wa2 = wv2[j0 * 3 + 2];
        float2 wb0 = wv2[j0 * 3 + 3], wb1 = wv2[j0 * 3 + 4], wb2 = wv2[j0 * 3 + 5];
        float wc0 = wc[j0], wc1 = wc[j0 + 1], bc0 = bc[j0], bc1 = bc[j0 + 1];
        float bv0 = bv[j0], bv1 = bv[j0 + 1];

        float s0 = 0.f, ss0 = 0.f, s1 = 0.f, ss1 = 0.f;
        #pragma unroll 4
        for (int m = 0; m < 32; m++) {
            int ln = wave * 32 + m;               // local node, wave-uniform
            int n = n0 + ln;
            const float* xr = &xs[ln * 6];
            float a0, a1;
            if (n < nc) {
                float xv = xr[0];
                a0 = xv * wc0 + bc0; a1 = xv * wc1 + bc1;
            } else {
                float x0 = xr[0], x1 = xr[1], x2 = xr[2], x3 = xr[3], x4 = xr[4], x5 = xr[5];
                a0 = bv0 + x0 * wa0.x + x1 * wa0.y + x2 * wa1.x + x3 * wa1.y + x4 * wa2.x + x5 * wa2.y;
                a1 = bv1 + x0 * wb0.x + x1 * wb0.y + x2 * wb1.x + x3 * wb1.y + x4 * wb2.x + x5 * wb2.y;
            }
            uint32 pk = packbf(ftanh(a0), ftanh(a1));
            h0u[(size_t)n * 64 + lane] = pk;
            float v0 = blo(pk), v1 = bhi(pk);     // stats on rounded values
            s0 += v0; ss0 += v0 * v0; s1 += v1; ss1 += v1 * v1;
        }
        sh[t] = s0; __syncthreads();
        if (t < 64) atomicAdd(&stats[2 * t], sh[t] + sh[t + 64] + sh[t + 128] + sh[t + 192]);
        __syncthreads(); sh[t] = s1; __syncthreads();
        if (t < 64) atomicAdd(&stats[2 * t + 1], sh[t] + sh[t + 64] + sh[t + 128] + sh[t + 192]);
        __syncthreads(); sh[t] = ss0; __syncthreads();
        if (t < 64) atomicAdd(&stats[128 + 2 * t], sh[t] + sh[t + 64] + sh[t + 128] + sh[t + 192]);
        __syncthreads(); sh[t] = ss1; __syncthreads();
        if (t < 64) atomicAdd(&stats[128 + 2 * t + 1], sh[t] + sh[t + 64] + sh[t + 128] + sh[t + 192]);
    } else if (b < 1056) {                        // ---- dense col sums ----
        int r0 = (b - 1024) * 8;
        float s = 0.f;
        for (int r = r0; r < r0 + 8; r++)
            s += (scen[r * 256 + t] >= THRE) ? 1.0f : 0.0f;
        atomicAdd(&fcol[t], s);
    } else {                                      // ---- W1 -> bf16 pack ----
        const float4* w4 = (const float4*)w1f;
        uint2* wo = (uint2*)w1bk;
        #pragma unroll
        for (int it = 0; it < 16; it++) {
            int fi = it * 256 + t;                // 4096 float4
            float4 w = w4[fi];
            wo[fi] = make_uint2(packbf(w.x, w.y), packbf(w.z, w.w));
        }
    }
    gbar(bar, 1057);

    // ================= P2: per-bin scan of block partials =================
    if (b < 256) {
        uint32* v  = (uint32*)smem;               // 512
        uint32* ps = (uint32*)(smem + 2048);      // 256
        int g = b;
        v[t]       = blkhist[t * 256 + g];
        v[t + 256] = blkhist[(t + 256) * 256 + g];
        __syncthreads();
        uint32 a0 = v[2 * t], a1 = v[2 * t + 1];
        ps[t] = a0 + a1; __syncthreads();
        for (int o = 1; o < 256; o <<= 1) {
            uint32 u = (t >= o) ? ps[t - o] : 0;
            __syncthreads();
            ps[t] += u;
            __syncthreads();
        }
        uint32 ex = ps[t] - (a0 + a1);            // exclusive over block pairs
        ((uint2*)blkoff)[g * 256 + t] = make_uint2(ex, ex + a0);
        if (t == 255) binsz[g] = ps[255];
    }
    gbar(bar, 1057);

    // ================= P3: scatter edges into bins =================
    if (b < 512) {
        uint32* ps = (uint32*)smem;               // 256
        uint32* bo = (uint32*)(smem + 1024);      // 256
        uint32* bh = (uint32*)(smem + 2048);      // 256
        uint32 s = binsz[t];
        ps[t] = s; __syncthreads();
        for (int o = 1; o < 256; o <<= 1) {
            uint32 u = (t >= o) ? ps[t - o] : 0;
            __syncthreads();
            ps[t] += u;
            __syncthreads();
        }
        bo[t] = (ps[t] - s) + blkoff[t * 512 + b];
        bh[t] = 0;
        __syncthreads();
        int e0 = b * 1024 + t * 4;
        int4 d4 = *(const int4*)(dst + e0);
        int4 s4 = *(const int4*)(src + e0);
        float4 w4 = *(const float4*)(ew + e0);
        int bin; uint32 r;
        bin = d4.x >> 8; r = atomicAdd(&bh[bin], 1u);
        ebin[bo[bin] + r] = make_uint2((uint32)s4.x | ((uint32)(d4.x & 255) << 16), __float_as_uint(w4.x));
        bin = d4.y >> 8; r = atomicAdd(&bh[bin], 1u);
        ebin[bo[bin] + r] = make_uint2((uint32)s4.y | ((uint32)(d4.y & 255) << 16), __float_as_uint(w4.y));
        bin = d4.z >> 8; r = atomicAdd(&bh[bin], 1u);
        ebin[bo[bin] + r] = make_uint2((uint32)s4.z | ((uint32)(d4.z & 255) << 16), __float_as_uint(w4.z));
        bin = d4.w >> 8; r = atomicAdd(&bh[bin], 1u);
        ebin[bo[bin] + r] = make_uint2((uint32)s4.w | ((uint32)(d4.w & 255) << 16), __float_as_uint(w4.w));
    }
    gbar(bar, 1057);

    // ================= P4: per-bin CSR build =================
    if (b < 256) {
        uint2* es    = (uint2*)smem;              // 24576B
        uint32* hist = (uint32*)(smem + 24576);   // 1024B
        int* sscan   = (int*)(smem + 25600);      // 1024B
        int* rloc    = (int*)(smem + 26624);      // 1024B
        float* dlv   = (float*)(smem + 27648);    // 1024B
        uint32* ubl  = (uint32*)(smem + 28672);   // 1024B
        int g = b;
        {
            uint32 s = binsz[t];
            sscan[t] = (int)s; __syncthreads();
            for (int o = 1; o < 256; o <<= 1) {
                int u = (t >= o) ? sscan[t - o] : 0;
                __syncthreads();
                sscan[t] += u;
                __syncthreads();
            }
            ubl[t] = (uint32)sscan[t] - s;
        }
        __syncthreads();
        int start = (int)ubl[g];
        int sz = min((int)binsz[g], 3072);
        int pb = start + g * 768;
        hist[t] = 0;
        __syncthreads();
        for (int i2 = t; i2 < sz; i2 += 256) {    // load + rank in one pass
            uint2 e = ebin[start + i2];
            int dl = (e.x >> 16) & 255;
            uint32 wfix = __float2uint_rn(__uint_as_float(e.y) * 262144.0f);
            uint32 h = atomicAdd(&hist[dl], (1u << 24) | wfix);
            e.x |= (h >> 24) << 24;               // rank (u8) into top byte
            es[i2] = e;
        }
        __syncthreads();
        uint32 hv = hist[t];
        int cnt = (int)(hv >> 24);
        float di = rsqrtf((float)(hv & 0xFFFFFFu) * 3.814697265625e-6f + 1.0f);
        dlv[t] = di;
        dinv[g * 256 + t] = di;
        cnts[g * 256 + t] = cnt;
        int pcnt = (cnt + 3) & ~3;
        sscan[t] = pcnt; __syncthreads();
        for (int o = 1; o < 256; o <<= 1) {
            int u = (t >= o) ? sscan[t - o] : 0;
            __syncthreads();
            sscan[t] += u;
            __syncthreads();
        }
        int rl = sscan[t] - pcnt;
        rloc[t] = rl;
        rowp[g * 256 + t] = pb + rl;
        __syncthreads();
        for (int i2 = t; i2 < sz; i2 += 256) {
            uint2 e = es[i2];
            int s2 = (int)(e.x & 0xFFFFu);
            int dl = (int)((e.x >> 16) & 255u);
            int r  = (int)(e.x >> 24);
            float w = __uint_as_float(e.y) * dlv[dl];
            epk[pb + rloc[dl] + r] = make_int2(s2, __float_as_int(w));
        }
        int basep = pb + rl;
        for (int q = cnt; q < pcnt; q++) epk[basep + q] = make_int2(g * 256 + t, 0);
    }
}

// ---------------------------------------------------------------------------
// GEMM1: xw = dinv ⊙ (BN1(h0) @ W1^T) via MFMA bf16. Unchanged (occupancy-
// critical: 53KB LDS, kept standalone).
// ---------------------------------------------------------------------------
__global__ __launch_bounds__(256) void k_gemm1f(
    const uint32* __restrict__ h0u, const uint32* __restrict__ w1bk,
    const float* __restrict__ g1, const float* __restrict__ bb1,
    const float* __restrict__ stats, ushort16* __restrict__ xws,
    const float* __restrict__ dinv)
{
    __shared__ short hn_s[64 * 136];    // bf16 bits, row-major, stride 136 (2-way max)
    __shared__ short w_s[128 * 136];
    __shared__ float sc[128], sf[128];
    int t = threadIdx.x;
    int blk = blockIdx.x;
    int row0 = blk * 64;

    if (t < 128) {
        float mu  = stats[t] * (1.0f / N_NODES);
        float var = stats[128 + t] * (1.0f / N_NODES) - mu * mu;
        float rs  = rsqrtf(fmaxf(var, 0.f) + BN_EPS);
        float s   = rs * g1[t];
        sc[t] = s;
        sf[t] = bb1[t] - mu * s;
    }
    __syncthreads();

    const uint4* h4 = (const uint4*)(h0u + (size_t)row0 * 64);
    #pragma unroll
    for (int it = 0; it < 4; it++) {
        int slot = it * 256 + t;
        int r = slot >> 4, k0 = (slot & 15) * 8;
        uint4 u = h4[slot];
        uint32 ua[4] = {u.x, u.y, u.z, u.w};
        uint32 o[4];
        #pragma unroll
        for (int m = 0; m < 4; m++) {
            int k = k0 + 2 * m;
            o[m] = packbf(blo(ua[m]) * sc[k] + sf[k], bhi(ua[m]) * sc[k + 1] + sf[k + 1]);
        }
        *(uint4*)&hn_s[r * 136 + k0] = make_uint4(o[0], o[1], o[2], o[3]);
    }
    const uint4* wv4 = (const uint4*)w1bk;
    #pragma unroll
    for (int it = 0; it < 8; it++) {
        int s2 = it * 256 + t;              // 2048 uint4 (8 bf16 each)
        int c = s2 >> 4, k0 = (s2 & 15) * 8;
        *(uint4*)&w_s[c * 136 + k0] = wv4[s2];
    }
    __syncthreads();

    int lane = t & 63, wave = t >> 6;
    int m16 = lane & 15, kh = lane >> 4;
    int mbase = wave * 16;
    f32x4 acc[8] = {};
    #pragma unroll
    for (int ks = 0; ks < 4; ks++) {
        short8 a = *(const short8*)&hn_s[(mbase + m16) * 136 + ks * 32 + kh * 8];
        #pragma unroll
        for (int ct = 0; ct < 8; ct++) {
            short8 bfr = *(const short8*)&w_s[(ct * 16 + m16) * 136 + ks * 32 + kh * 8];
            acc[ct] = __builtin_amdgcn_mfma_f32_16x16x32_bf16(a, bfr, acc[ct], 0, 0, 0);
        }
    }
    float dvr[4];
    #pragma unroll
    for (int r = 0; r < 4; r++) dvr[r] = dinv[row0 + mbase + kh * 4 + r];
    #pragma unroll
    for (int ct = 0; ct < 8; ct++) {
        int col = ct * 16 + m16;
        #pragma unroll
        for (int r = 0; r < 4; r++) {
            int row = mbase + kh * 4 + r;
            bf16 hv = __float2bfloat16(acc[ct][r] * dvr[r]);
            unsigned short us; __builtin_memcpy(&us, &hv, 2);
            xws[(size_t)(row0 + row) * 128 + col] = us;
        }
    }
}

// ---------------------------------------------------------------------------
// GATHER + fused BN2 stats. Unchanged (occupancy-critical: latency-bound,
// needs 32 waves/CU, kept standalone). 2048 blocks x 256, 32 nodes/block.
// ---------------------------------------------------------------------------
__global__ __launch_bounds__(256) void k_gather(
    const int* __restrict__ rowp, const int* __restrict__ cnts,
    const int2* __restrict__ epk, const uint32* __restrict__ xwu,
    const float* __restrict__ dinv, const float2* __restrict__ b1c2,
    uint32* __restrict__ aggu, float* __restrict__ stats2r)
{
    __shared__ float sh[256];
    int t = threadIdx.x, b = blockIdx.x;
    int lane = t & 63, wave = t >> 6;
    float2 bb = b1c2[lane];
    float s0 = 0.f, ss0 = 0.f, s1 = 0.f, ss1 = 0.f;
    for (int it = 0; it < 8; it++) {
        int n = b * 32 + it * 4 + wave;
        int st = rowp[n];
        int pcnt = (cnts[n] + 3) & ~3;
        float di = dinv[n];
        uint32 u0 = xwu[(size_t)n * 64 + lane];
        float ax = di * blo(u0) + bb.x;
        float ay = di * bhi(u0) + bb.y;
        int en = st + pcnt;
        for (int p = st; p < en; p += 4) {
            int2 q0 = epk[p], q1 = epk[p + 1], q2 = epk[p + 2], q3 = epk[p + 3];
            uint32 v0 = xwu[(size_t)q0.x * 64 + lane];
            uint32 v1 = xwu[(size_t)q1.x * 64 + lane];
            uint32 v2 = xwu[(size_t)q2.x * 64 + lane];
            uint32 v3 = xwu[(size_t)q3.x * 64 + lane];
            float w0 = __int_as_float(q0.y), w1 = __int_as_float(q1.y);
            float w2 = __int_as_float(q2.y), w3 = __int_as_float(q3.y);
            ax += w0 * blo(v0) + w1 * blo(v1) + w2 * blo(v2) + w3 * blo(v3);
            ay += w0 * bhi(v0) + w1 * bhi(v1) + w2 * bhi(v2) + w3 * bhi(v3);
        }
        uint32 pk = packbf(ax, ay);
        aggu[(size_t)n * 64 + lane] = pk;
        float v0 = blo(pk), v1 = bhi(pk);
        s0 += v0; ss0 += v0 * v0; s1 += v1; ss1 += v1 * v1;
    }
    float* st2 = stats2r + (b & 7) * 256;
    sh[t] = s0; __syncthreads();
    if (t < 64) atomicAdd(&st2[2 * t], sh[t] + sh[t + 64] + sh[t + 128] + sh[t + 192]);
    __syncthreads(); sh[t] = s1; __syncthreads();
    if (t < 64) atomicAdd(&st2[2 * t + 1], sh[t] + sh[t + 64] + sh[t + 128] + sh[t + 192]);
    __syncthreads(); sh[t] = ss0; __syncthreads();
    if (t < 64) atomicAdd(&st2[128 + 2 * t], sh[t] + sh[t + 64] + sh[t + 128] + sh[t + 192]);
    __syncthreads(); sh[t] = ss1; __syncthreads();
    if (t < 64) atomicAdd(&st2[128 + 2 * t + 1], sh[t] + sh[t + 64] + sh[t + 128] + sh[t + 192]);
}

// ---------------------------------------------------------------------------
// TAIL kernel: 256 blocks x 256 (1 block/CU — trivially co-resident), 3 grid
// barriers. Bodies = mega P7-P10 (verified rounds 4/5).
//  P7  pool + gemm2 -> z1
//  P8  dense GCN1 -> y1 + BN3 stats
//  P9  gemm3: z2 = tanh(BN3(y1)) @ W3^T
//  P10 dense GCN2 -> out + mean fold
// ---------------------------------------------------------------------------
__global__ __launch_bounds__(256) void k_tail(
    const uint32* __restrict__ aggu, const float* __restrict__ stats2r,
    const float* __restrict__ g2, const float* __restrict__ bb2,
    const float* __restrict__ w2, float* __restrict__ z1,
    const float* __restrict__ scen, const float* __restrict__ fcol,
    const float* __restrict__ b2c, float* __restrict__ y1,
    float* __restrict__ stats3r, const float* __restrict__ g3,
    const float* __restrict__ bb3, const float* __restrict__ w3,
    float* __restrict__ z2, const float* __restrict__ b3c,
    float* __restrict__ out, float* __restrict__ meanr,
    int* __restrict__ ctr, int* __restrict__ bar)
{
    __shared__ __align__(16) uchar smem[2560];
    __shared__ int flagP10;
    int t = threadIdx.x;
    int b = blockIdx.x;

    // ================= P7: pool + gemm2 =================
    {
        float* sc   = (float*)smem;             // 128
        float* sf   = (float*)(smem + 512);     // 128
        float* sh   = (float*)(smem + 1024);    // 256
        float* prow = (float*)(smem + 2048);    // 128
        int g = b;
        if (t < 128) {
            float su = 0.f, sq = 0.f;
            #pragma unroll
            for (int r = 0; r < 8; r++) {
                su += stats2r[r * 256 + t];
                sq += stats2r[r * 256 + 128 + t];
            }
            float mu  = su * (1.0f / N_NODES);
            float var = sq * (1.0f / N_NODES) - mu * mu;
            float rs  = rsqrtf(fmaxf(var, 0.f) + BN_EPS);
            float s   = rs * g2[t];
            sc[t] = s;
            sf[t] = bb2[t] - mu * s;
        }
        __syncthreads();
        int c = t & 63, grp = t >> 6;           // 4 groups x 64 rows
        float c0s = sc[2 * c], c0f = sf[2 * c], c1s = sc[2 * c + 1], c1f = sf[2 * c + 1];
        const uint32* base = aggu + (size_t)g * 256 * 64;
        float s0 = 0.f, s1 = 0.f;
        for (int r = grp * 64; r < grp * 64 + 64; r++) {
            uint32 u = base[r * 64 + c];
            s0 += ftanh(blo(u) * c0s + c0f);
            s1 += ftanh(bhi(u) * c1s + c1f);
        }
        sh[t] = s0; __syncthreads();
        if (t < 64) {
            float acc = sh[t] + sh[t + 64] + sh[t + 128] + sh[t + 192];
            prow[2 * t] = acc * (1.0f / 256.0f);
        }
        __syncthreads(); sh[t] = s1; __syncthreads();
        if (t < 64) {
            float acc = sh[t] + sh[t + 64] + sh[t + 128] + sh[t + 192];
            prow[2 * t + 1] = acc * (1.0f / 256.0f);
        }
        __syncthreads();
        float accv = 0.f;
        const float* wr = w2 + t * 128;
        for (int k = 0; k < 128; k++) accv += prow[k] * wr[k];
        z1[g * 256 + t] = accv;
    }
    gbar(bar, 256);

    // ================= P8: dense GCN1 + BN3 stats =================
    {
        float* wk = (float*)smem;
        int i = b;
        float aa = (scen[t * 256 + i] >= THRE) ? 1.0f : 0.0f;
        if (t == i) aa += 1.0f;
        wk[t] = aa * rsqrtf(fcol[t] + 1.0f);
        __syncthreads();
        float acc = 0.f;
        for (int k = 0; k < 256; k++) acc += wk[k] * z1[k * 256 + t];
        float v = rsqrtf(fcol[i] + 1.0f) * acc + b2c[t];
        y1[i * 256 + t] = v;
        float* s3 = stats3r + (i & 7) * 512;
        atomicAdd(&s3[t], v);
        atomicAdd(&s3[256 + t], v * v);
    }
    gbar(bar, 256);

    // ================= P9: gemm3 =================
    {
        float* row = (float*)smem;
        int i = b;
        {
            float s = 0.f, ss = 0.f;
            #pragma unroll
            for (int r = 0; r < 8; r++) {
                s  += stats3r[r * 512 + t];
                ss += stats3r[r * 512 + 256 + t];
            }
            float mu  = s * (1.0f / 256.0f);
            float var = ss * (1.0f / 256.0f) - mu * mu;
            float rs  = rsqrtf(fmaxf(var, 0.f) + BN_EPS);
            float scj = rs * g3[t];
            float sfj = bb3[t] - mu * scj;
            row[t] = ftanh(y1[i * 256 + t] * scj + sfj);
        }
        __syncthreads();
        if (t < 128) {
            float acc = 0.f;
            const float* wr = w3 + t * 256;
            for (int k = 0; k < 256; k++) acc += row[k] * wr[k];
            z2[i * 128 + t] = acc;
        }
    }
    gbar(bar, 256);

    // ================= P10: dense GCN2 + mean fold =================
    {
        float* wk = (float*)smem;
        int i = b;
        {
            float aa = (scen[t * 256 + i] >= THRE) ? 1.0f : 0.0f;
            if (t == i) aa += 1.0f;
            wk[t] = aa * rsqrtf(fcol[t] + 1.0f);
        }
        __syncthreads();
        if (t < 128) {
            float acc = 0.f;
            for (int k = 0; k < 256; k++) acc += wk[k] * z2[k * 128 + t];
            float v = ftanh(rsqrtf(fcol[i] + 1.0f) * acc + b3c[t]);
            out[i * 128 + t] = v;
            atomicAdd(&meanr[(i & 7) * 128 + t], v);
        }
        __syncthreads();
        if (t == 0) {
            __threadfence();
            flagP10 = (atomicAdd(ctr, 1) == 255) ? 1 : 0;
        }
        __syncthreads();
        if (flagP10) {
            __threadfence();
            if (t < 128) {
                float s = 0.f;
                #pragma unroll
                for (int r = 0; r < 8; r++) s += meanr[r * 128 + t];
                out[S_GRAPH * 128 + t] = s * (1.0f / 256.0f);
            }
        }
    }
}

// ---------------------------------------------------------------------------
extern "C" void kernel_launch(void* const* d_in, const int* in_sizes, int n_in,
                              void* d_out, int out_size, void* d_ws, size_t ws_size,
                              hipStream_t stream)
{
    const float* x        = (const float*)d_in[0];
    const float* edge_attr= (const float*)d_in[1];
    const float* scen     = (const float*)d_in[2];
    const float* wv       = (const float*)d_in[3];
    const float* bv       = (const float*)d_in[4];
    const float* wc       = (const float*)d_in[5];
    const float* bc       = (const float*)d_in[6];
    const float* w1       = (const float*)d_in[7];
    const float* b1c      = (const float*)d_in[8];
    const float* w2       = (const float*)d_in[9];
    const float* b2c      = (const float*)d_in[10];
    const float* w3       = (const float*)d_in[11];
    const float* b3c      = (const float*)d_in[12];
    const float* g1       = (const float*)d_in[13];
    const float* bb1      = (const float*)d_in[14];
    const float* g2       = (const float*)d_in[15];
    const float* bb2      = (const float*)d_in[16];
    const float* g3       = (const float*)d_in[17];
    const float* bb3      = (const float*)d_in[18];
    const int*  ei        = (const int*)d_in[20];
    const int*  nconp     = (const int*)d_in[22];
    const int*  src = ei;
    const int*  dst = ei + N_EDGES;

    float* wsf = (float*)d_ws;
    uint32*   h0u  = (uint32*)wsf;            // 16.7MB, dead after gemm1
    uint32*   aggu = (uint32*)wsf;            // alias
    uint32*   xwu  = (uint32*)(wsf + 4194304);// 16.7MB
    // zero-init block: stats, replicas, fcol, meanr, counters
    float* zb      = wsf + 8388608;
    float* stats1  = zb;                      // 512
    float* stats2r = zb + 512;                // 8*256 = 2048
    float* stats3r = zb + 2560;               // 8*512 = 4096
    float* fcol    = zb + 6656;               // 256
    float* meanr   = zb + 6912;               // 1024
    int*   ctrs    = (int*)(zb + 7936);       // 8: [1] fold, [2,3] barA, [4,5] barB
    const int ZN   = 7944;
    float* deg     = zb + ZN;                 // 65536 (dinv)
    int*   rowp    = (int*)(deg + 65536);     // 65536 (absolute padded offsets)
    int*   cnts    = rowp + 65536;            // 65536
    uint32* blkhist= (uint32*)(cnts + 65536); // 512*256 [block][bin]
    uint32* blkoff = blkhist + 131072;        // 256*512 [bin][block]
    uint32* binsz  = blkoff + 131072;         // 256
    uint2* ebin    = (uint2*)(binsz + 256 + 512); // 524288 uint2 (binned edges)
    int2*  epk     = (int2*)(ebin + 524288);  // 720896 int2 (padded CSR)
    uint32* w1bk   = (uint32*)(epk + 720896); // 8192 (32KB bf16 W1)
    float* z1      = (float*)(w1bk + 8192);   // 65536
    float* y1      = z1 + 65536;              // 65536
    float* z2      = y1 + 65536;              // 32768

    float* out = (float*)d_out;

    hipMemsetAsync(zb, 0, ZN * sizeof(float), stream);

    k_front<<<1057, 256, 0, stream>>>(x, wv, bv, wc, bc, nconp, h0u, stats1,
                                      src, dst, edge_attr, blkhist, blkoff,
                                      binsz, scen, fcol, w1, w1bk,
                                      deg, rowp, cnts, ebin, epk, &ctrs[2]);
    k_gemm1f<<<1024, 256, 0, stream>>>(h0u, w1bk, g1, bb1, stats1, (ushort16*)xwu, deg);
    k_gather<<<2048, 256, 0, stream>>>(rowp, cnts, epk, xwu, deg,
                                       (const float2*)b1c, aggu, stats2r);
    k_tail<<<256, 256, 0, stream>>>(aggu, stats2r, g2, bb2, w2, z1,
                                    scen, fcol, b2c, y1, stats3r,
                                    g3, bb3, w3, z2, b3c, out, meanr,
                                    &ctrs[1], &ctrs[4]);
}

// Round 8
// 549.546 us; speedup vs baseline: 1.0055x; 1.0055x over previous
//
#include <hip/hip_runtime.h>
#include <hip/hip_bf16.h>
#include <cstddef>

#define N_NODES 65536
#define N_EDGES 524288
#define S_GRAPH 256
#define BN_EPS 1e-5f
#define THRE 0.7f

typedef __hip_bfloat16 bf16;
typedef unsigned int uint32;
typedef unsigned char uchar;
typedef unsigned short ushort16;
typedef __attribute__((ext_vector_type(8))) short short8;
typedef __attribute__((ext_vector_type(4))) float f32x4;

__device__ __forceinline__ float blo(uint32 u) { return __uint_as_float(u << 16); }
__device__ __forceinline__ float bhi(uint32 u) { return __uint_as_float(u & 0xffff0000u); }

__device__ __forceinline__ uint32 packbf(float a, float b)
{
    bf16 ha = __float2bfloat16(a), hb = __float2bfloat16(b);
    unsigned short ua, ub;
    __builtin_memcpy(&ua, &ha, 2); __builtin_memcpy(&ub, &hb, 2);
    return (uint32)ua | ((uint32)ub << 16);
}

// fast tanh: 1 - 2/(e^{2x}+1); |err| ~1e-6, far below bf16 rounding (2^-9)
__device__ __forceinline__ float ftanh(float x)
{
    float e = __builtin_amdgcn_exp2f(x * 2.8853900817779268f);  // 2*log2(e)
    return 1.0f - 2.0f * __builtin_amdgcn_rcpf(e + 1.0f);
}

// device-scope sense-reversal grid barrier (all nblk blocks must call).
// v3: SYSTEM-scope relaxed polls. r7 post-mortem: agent-relaxed polls are
// served by the local XCD L2, which holds the STALE generation (memory-side
// RMWs don't invalidate L2 copies) -> each barrier waited ~60us for natural
// eviction. SYSTEM-scope loads emit sc0+sc1 (bypass L1 AND L2) -> fresh read
// of the coherent point each poll, no invalidation traffic (reads don't
// serialize like RMWs). Data ordering: one release fence (L2 wb) before
// arrival, one acquire fence (L2 inv) after the flip (verified r5/r6).
__device__ __forceinline__ void gbar(int* bar, int nblk)
{
    __syncthreads();
    if (threadIdx.x == 0) {
        __builtin_amdgcn_fence(__ATOMIC_RELEASE, "agent");   // wb dirty L2 once
        int gen = __hip_atomic_load(bar + 1, __ATOMIC_RELAXED, __HIP_MEMORY_SCOPE_SYSTEM);
        if (__hip_atomic_fetch_add(bar, 1, __ATOMIC_RELAXED, __HIP_MEMORY_SCOPE_AGENT) == nblk - 1) {
            __hip_atomic_store(bar, 0, __ATOMIC_RELAXED, __HIP_MEMORY_SCOPE_AGENT);
            __hip_atomic_fetch_add(bar + 1, 1, __ATOMIC_RELAXED, __HIP_MEMORY_SCOPE_AGENT);
        } else {
            while (__hip_atomic_load(bar + 1, __ATOMIC_RELAXED, __HIP_MEMORY_SCOPE_SYSTEM) == gen)
                __builtin_amdgcn_s_sleep(8);
        }
        __builtin_amdgcn_fence(__ATOMIC_ACQUIRE, "agent");   // inv stale L2 once
    }
    __syncthreads();
}

// ---------------------------------------------------------------------------
// FRONT kernel: 1057 blocks x 256, 3 grid barriers. 29.7KB LDS -> 5 blk/CU
// (1280 co-resident >= 1057); __launch_bounds__(256,5) caps VGPR at 102.
//  P1: [0..511] bin hist (bin=dst>>8) -> blkhist | [512..1023] node MLP +
//      BN1 stats | [1024..1055] fcol | [1056] W1->bf16
//  P2: per-bin scan of 512 block partials -> blkoff, binsz     [b<256]
//  P3: scatter edges into bin regions (local binsz scan)       [b<512]
//  P4: per-bin CSR build -> dinv, rowp, cnts, epk              [b<256]
// ---------------------------------------------------------------------------
__global__ __launch_bounds__(256, 5) void k_front(
    const float* __restrict__ x, const float* __restrict__ wv,
    const float* __restrict__ bv, const float* __restrict__ wc,
    const float* __restrict__ bc, const int* __restrict__ nconp,
    uint32* __restrict__ h0u, float* __restrict__ stats,
    const int* __restrict__ src, const int* __restrict__ dst,
    const float* __restrict__ ew, uint32* __restrict__ blkhist,
    uint32* __restrict__ blkoff, uint32* __restrict__ binsz,
    const float* __restrict__ scen, float* __restrict__ fcol,
    const float* __restrict__ w1f, uint32* __restrict__ w1bk,
    float* __restrict__ dinv, int* __restrict__ rowp, int* __restrict__ cnts,
    uint2* __restrict__ ebin, int2* __restrict__ epk, int* __restrict__ bar)
{
    __shared__ __align__(16) uchar smem[29696];
    int t = threadIdx.x;
    int b = blockIdx.x;

    // ================= P1 =================
    if (b < 512) {                                // ---- bin histogram ----
        uint32* bh = (uint32*)smem;
        bh[t] = 0;
        __syncthreads();
        int e0 = b * 1024 + t * 4;
        int4 d4 = *(const int4*)(dst + e0);
        atomicAdd(&bh[d4.x >> 8], 1u);
        atomicAdd(&bh[d4.y >> 8], 1u);
        atomicAdd(&bh[d4.z >> 8], 1u);
        atomicAdd(&bh[d4.w >> 8], 1u);
        __syncthreads();
        blkhist[b * 256 + t] = bh[t];
    } else if (b < 1024) {                        // ---- node MLP ----
        float* xs = (float*)smem;                 // 768 floats
        float* sh = (float*)(smem + 3072);        // 256 floats
        int n0 = (b - 512) * 128;
        if (t < 192) ((float4*)xs)[t] = ((const float4*)(x + (size_t)n0 * 6))[t];
        __syncthreads();

        int nc = *nconp;
        int lane = t & 63, wave = t >> 6;
        int j0 = 2 * lane;
        const float2* wv2 = (const float2*)wv;
        float2 wa0 = wv2[j0 * 3], wa1 = wv2[j0 * 3 + 1], wa2 = wv2[j0 * 3 + 2];
        float2 wb0 = wv2[j0 * 3 + 3], wb1 = wv2[j0 * 3 + 4], wb2 = wv2[j0 * 3 + 5];
        float wc0 = wc[j0], wc1 = wc[j0 + 1], bc0 = bc[j0], bc1 = bc[j0 + 1];
        float bv0 = bv[j0], bv1 = bv[j0 + 1];

        float s0 = 0.f, ss0 = 0.f, s1 = 0.f, ss1 = 0.f;
        #pragma unroll 4
        for (int m = 0; m < 32; m++) {
            int ln = wave * 32 + m;               // local node, wave-uniform
            int n = n0 + ln;
            const float* xr = &xs[ln * 6];
            float a0, a1;
            if (n < nc) {
                float xv = xr[0];
                a0 = xv * wc0 + bc0; a1 = xv * wc1 + bc1;
            } else {
                float x0 = xr[0], x1 = xr[1], x2 = xr[2], x3 = xr[3], x4 = xr[4], x5 = xr[5];
                a0 = bv0 + x0 * wa0.x + x1 * wa0.y + x2 * wa1.x + x3 * wa1.y + x4 * wa2.x + x5 * wa2.y;
                a1 = bv1 + x0 * wb0.x + x1 * wb0.y + x2 * wb1.x + x3 * wb1.y + x4 * wb2.x + x5 * wb2.y;
            }
            uint32 pk = packbf(ftanh(a0), ftanh(a1));
            h0u[(size_t)n * 64 + lane] = pk;
            float v0 = blo(pk), v1 = bhi(pk);     // stats on rounded values
            s0 += v0; ss0 += v0 * v0; s1 += v1; ss1 += v1 * v1;
        }
        sh[t] = s0; __syncthreads();
        if (t < 64) atomicAdd(&stats[2 * t], sh[t] + sh[t + 64] + sh[t + 128] + sh[t + 192]);
        __syncthreads(); sh[t] = s1; __syncthreads();
        if (t < 64) atomicAdd(&stats[2 * t + 1], sh[t] + sh[t + 64] + sh[t + 128] + sh[t + 192]);
        __syncthreads(); sh[t] = ss0; __syncthreads();
        if (t < 64) atomicAdd(&stats[128 + 2 * t], sh[t] + sh[t + 64] + sh[t + 128] + sh[t + 192]);
        __syncthreads(); sh[t] = ss1; __syncthreads();
        if (t < 64) atomicAdd(&stats[128 + 2 * t + 1], sh[t] + sh[t + 64] + sh[t + 128] + sh[t + 192]);
    } else if (b < 1056) {                        // ---- dense col sums ----
        int r0 = (b - 1024) * 8;
        float s = 0.f;
        for (int r = r0; r < r0 + 8; r++)
            s += (scen[r * 256 + t] >= THRE) ? 1.0f : 0.0f;
        atomicAdd(&fcol[t], s);
    } else {                                      // ---- W1 -> bf16 pack ----
        const float4* w4 = (const float4*)w1f;
        uint2* wo = (uint2*)w1bk;
        #pragma unroll
        for (int it = 0; it < 16; it++) {
            int fi = it * 256 + t;                // 4096 float4
            float4 w = w4[fi];
            wo[fi] = make_uint2(packbf(w.x, w.y), packbf(w.z, w.w));
        }
    }
    gbar(bar, 1057);

    // ================= P2: per-bin scan of block partials =================
    if (b < 256) {
        uint32* v  = (uint32*)smem;               // 512
        uint32* ps = (uint32*)(smem + 2048);      // 256
        int g = b;
        v[t]       = blkhist[t * 256 + g];
        v[t + 256] = blkhist[(t + 256) * 256 + g];
        __syncthreads();
        uint32 a0 = v[2 * t], a1 = v[2 * t + 1];
        ps[t] = a0 + a1; __syncthreads();
        for (int o = 1; o < 256; o <<= 1) {
            uint32 u = (t >= o) ? ps[t - o] : 0;
            __syncthreads();
            ps[t] += u;
            __syncthreads();
        }
        uint32 ex = ps[t] - (a0 + a1);            // exclusive over block pairs
        ((uint2*)blkoff)[g * 256 + t] = make_uint2(ex, ex + a0);
        if (t == 255) binsz[g] = ps[255];
    }
    gbar(bar, 1057);

    // ================= P3: scatter edges into bins =================
    if (b < 512) {
        uint32* ps = (uint32*)smem;               // 256
        uint32* bo = (uint32*)(smem + 1024);      // 256
        uint32* bh = (uint32*)(smem + 2048);      // 256
        uint32 s = binsz[t];
        ps[t] = s; __syncthreads();
        for (int o = 1; o < 256; o <<= 1) {
            uint32 u = (t >= o) ? ps[t - o] : 0;
            __syncthreads();
            ps[t] += u;
            __syncthreads();
        }
        bo[t] = (ps[t] - s) + blkoff[t * 512 + b];
        bh[t] = 0;
        __syncthreads();
        int e0 = b * 1024 + t * 4;
        int4 d4 = *(const int4*)(dst + e0);
        int4 s4 = *(const int4*)(src + e0);
        float4 w4 = *(const float4*)(ew + e0);
        int bin; uint32 r;
        bin = d4.x >> 8; r = atomicAdd(&bh[bin], 1u);
        ebin[bo[bin] + r] = make_uint2((uint32)s4.x | ((uint32)(d4.x & 255) << 16), __float_as_uint(w4.x));
        bin = d4.y >> 8; r = atomicAdd(&bh[bin], 1u);
        ebin[bo[bin] + r] = make_uint2((uint32)s4.y | ((uint32)(d4.y & 255) << 16), __float_as_uint(w4.y));
        bin = d4.z >> 8; r = atomicAdd(&bh[bin], 1u);
        ebin[bo[bin] + r] = make_uint2((uint32)s4.z | ((uint32)(d4.z & 255) << 16), __float_as_uint(w4.z));
        bin = d4.w >> 8; r = atomicAdd(&bh[bin], 1u);
        ebin[bo[bin] + r] = make_uint2((uint32)s4.w | ((uint32)(d4.w & 255) << 16), __float_as_uint(w4.w));
    }
    gbar(bar, 1057);

    // ================= P4: per-bin CSR build =================
    if (b < 256) {
        uint2* es    = (uint2*)smem;              // 24576B
        uint32* hist = (uint32*)(smem + 24576);   // 1024B
        int* sscan   = (int*)(smem + 25600);      // 1024B
        int* rloc    = (int*)(smem + 26624);      // 1024B
        float* dlv   = (float*)(smem + 27648);    // 1024B
        uint32* ubl  = (uint32*)(smem + 28672);   // 1024B
        int g = b;
        {
            uint32 s = binsz[t];
            sscan[t] = (int)s; __syncthreads();
            for (int o = 1; o < 256; o <<= 1) {
                int u = (t >= o) ? sscan[t - o] : 0;
                __syncthreads();
                sscan[t] += u;
                __syncthreads();
            }
            ubl[t] = (uint32)sscan[t] - s;
        }
        __syncthreads();
        int start = (int)ubl[g];
        int sz = min((int)binsz[g], 3072);
        int pb = start + g * 768;
        hist[t] = 0;
        __syncthreads();
        for (int i2 = t; i2 < sz; i2 += 256) {    // load + rank in one pass
            uint2 e = ebin[start + i2];
            int dl = (e.x >> 16) & 255;
            uint32 wfix = __float2uint_rn(__uint_as_float(e.y) * 262144.0f);
            uint32 h = atomicAdd(&hist[dl], (1u << 24) | wfix);
            e.x |= (h >> 24) << 24;               // rank (u8) into top byte
            es[i2] = e;
        }
        __syncthreads();
        uint32 hv = hist[t];
        int cnt = (int)(hv >> 24);
        float di = rsqrtf((float)(hv & 0xFFFFFFu) * 3.814697265625e-6f + 1.0f);
        dlv[t] = di;
        dinv[g * 256 + t] = di;
        cnts[g * 256 + t] = cnt;
        int pcnt = (cnt + 3) & ~3;
        sscan[t] = pcnt; __syncthreads();
        for (int o = 1; o < 256; o <<= 1) {
            int u = (t >= o) ? sscan[t - o] : 0;
            __syncthreads();
            sscan[t] += u;
            __syncthreads();
        }
        int rl = sscan[t] - pcnt;
        rloc[t] = rl;
        rowp[g * 256 + t] = pb + rl;
        __syncthreads();
        for (int i2 = t; i2 < sz; i2 += 256) {
            uint2 e = es[i2];
            int s2 = (int)(e.x & 0xFFFFu);
            int dl = (int)((e.x >> 16) & 255u);
            int r  = (int)(e.x >> 24);
            float w = __uint_as_float(e.y) * dlv[dl];
            epk[pb + rloc[dl] + r] = make_int2(s2, __float_as_int(w));
        }
        int basep = pb + rl;
        for (int q = cnt; q < pcnt; q++) epk[basep + q] = make_int2(g * 256 + t, 0);
    }
}

// ---------------------------------------------------------------------------
// GEMM1: xw = dinv ⊙ (BN1(h0) @ W1^T) via MFMA bf16. Unchanged (occupancy-
// critical: 53KB LDS, kept standalone).
// ---------------------------------------------------------------------------
__global__ __launch_bounds__(256) void k_gemm1f(
    const uint32* __restrict__ h0u, const uint32* __restrict__ w1bk,
    const float* __restrict__ g1, const float* __restrict__ bb1,
    const float* __restrict__ stats, ushort16* __restrict__ xws,
    const float* __restrict__ dinv)
{
    __shared__ short hn_s[64 * 136];    // bf16 bits, row-major, stride 136 (2-way max)
    __shared__ short w_s[128 * 136];
    __shared__ float sc[128], sf[128];
    int t = threadIdx.x;
    int blk = blockIdx.x;
    int row0 = blk * 64;

    if (t < 128) {
        float mu  = stats[t] * (1.0f / N_NODES);
        float var = stats[128 + t] * (1.0f / N_NODES) - mu * mu;
        float rs  = rsqrtf(fmaxf(var, 0.f) + BN_EPS);
        float s   = rs * g1[t];
        sc[t] = s;
        sf[t] = bb1[t] - mu * s;
    }
    __syncthreads();

    const uint4* h4 = (const uint4*)(h0u + (size_t)row0 * 64);
    #pragma unroll
    for (int it = 0; it < 4; it++) {
        int slot = it * 256 + t;
        int r = slot >> 4, k0 = (slot & 15) * 8;
        uint4 u = h4[slot];
        uint32 ua[4] = {u.x, u.y, u.z, u.w};
        uint32 o[4];
        #pragma unroll
        for (int m = 0; m < 4; m++) {
            int k = k0 + 2 * m;
            o[m] = packbf(blo(ua[m]) * sc[k] + sf[k], bhi(ua[m]) * sc[k + 1] + sf[k + 1]);
        }
        *(uint4*)&hn_s[r * 136 + k0] = make_uint4(o[0], o[1], o[2], o[3]);
    }
    const uint4* wv4 = (const uint4*)w1bk;
    #pragma unroll
    for (int it = 0; it < 8; it++) {
        int s2 = it * 256 + t;              // 2048 uint4 (8 bf16 each)
        int c = s2 >> 4, k0 = (s2 & 15) * 8;
        *(uint4*)&w_s[c * 136 + k0] = wv4[s2];
    }
    __syncthreads();

    int lane = t & 63, wave = t >> 6;
    int m16 = lane & 15, kh = lane >> 4;
    int mbase = wave * 16;
    f32x4 acc[8] = {};
    #pragma unroll
    for (int ks = 0; ks < 4; ks++) {
        short8 a = *(const short8*)&hn_s[(mbase + m16) * 136 + ks * 32 + kh * 8];
        #pragma unroll
        for (int ct = 0; ct < 8; ct++) {
            short8 bfr = *(const short8*)&w_s[(ct * 16 + m16) * 136 + ks * 32 + kh * 8];
            acc[ct] = __builtin_amdgcn_mfma_f32_16x16x32_bf16(a, bfr, acc[ct], 0, 0, 0);
        }
    }
    float dvr[4];
    #pragma unroll
    for (int r = 0; r < 4; r++) dvr[r] = dinv[row0 + mbase + kh * 4 + r];
    #pragma unroll
    for (int ct = 0; ct < 8; ct++) {
        int col = ct * 16 + m16;
        #pragma unroll
        for (int r = 0; r < 4; r++) {
            int row = mbase + kh * 4 + r;
            bf16 hv = __float2bfloat16(acc[ct][r] * dvr[r]);
            unsigned short us; __builtin_memcpy(&us, &hv, 2);
            xws[(size_t)(row0 + row) * 128 + col] = us;
        }
    }
}

// ---------------------------------------------------------------------------
// GATHER + fused BN2 stats. Unchanged (occupancy-critical: latency-bound,
// needs 32 waves/CU, kept standalone). 2048 blocks x 256, 32 nodes/block.
// ---------------------------------------------------------------------------
__global__ __launch_bounds__(256) void k_gather(
    const int* __restrict__ rowp, const int* __restrict__ cnts,
    const int2* __restrict__ epk, const uint32* __restrict__ xwu,
    const float* __restrict__ dinv, const float2* __restrict__ b1c2,
    uint32* __restrict__ aggu, float* __restrict__ stats2r)
{
    __shared__ float sh[256];
    int t = threadIdx.x, b = blockIdx.x;
    int lane = t & 63, wave = t >> 6;
    float2 bb = b1c2[lane];
    float s0 = 0.f, ss0 = 0.f, s1 = 0.f, ss1 = 0.f;
    for (int it = 0; it < 8; it++) {
        int n = b * 32 + it * 4 + wave;
        int st = rowp[n];
        int pcnt = (cnts[n] + 3) & ~3;
        float di = dinv[n];
        uint32 u0 = xwu[(size_t)n * 64 + lane];
        float ax = di * blo(u0) + bb.x;
        float ay = di * bhi(u0) + bb.y;
        int en = st + pcnt;
        for (int p = st; p < en; p += 4) {
            int2 q0 = epk[p], q1 = epk[p + 1], q2 = epk[p + 2], q3 = epk[p + 3];
            uint32 v0 = xwu[(size_t)q0.x * 64 + lane];
            uint32 v1 = xwu[(size_t)q1.x * 64 + lane];
            uint32 v2 = xwu[(size_t)q2.x * 64 + lane];
            uint32 v3 = xwu[(size_t)q3.x * 64 + lane];
            float w0 = __int_as_float(q0.y), w1 = __int_as_float(q1.y);
            float w2 = __int_as_float(q2.y), w3 = __int_as_float(q3.y);
            ax += w0 * blo(v0) + w1 * blo(v1) + w2 * blo(v2) + w3 * blo(v3);
            ay += w0 * bhi(v0) + w1 * bhi(v1) + w2 * bhi(v2) + w3 * bhi(v3);
        }
        uint32 pk = packbf(ax, ay);
        aggu[(size_t)n * 64 + lane] = pk;
        float v0 = blo(pk), v1 = bhi(pk);
        s0 += v0; ss0 += v0 * v0; s1 += v1; ss1 += v1 * v1;
    }
    float* st2 = stats2r + (b & 7) * 256;
    sh[t] = s0; __syncthreads();
    if (t < 64) atomicAdd(&st2[2 * t], sh[t] + sh[t + 64] + sh[t + 128] + sh[t + 192]);
    __syncthreads(); sh[t] = s1; __syncthreads();
    if (t < 64) atomicAdd(&st2[2 * t + 1], sh[t] + sh[t + 64] + sh[t + 128] + sh[t + 192]);
    __syncthreads(); sh[t] = ss0; __syncthreads();
    if (t < 64) atomicAdd(&st2[128 + 2 * t], sh[t] + sh[t + 64] + sh[t + 128] + sh[t + 192]);
    __syncthreads(); sh[t] = ss1; __syncthreads();
    if (t < 64) atomicAdd(&st2[128 + 2 * t + 1], sh[t] + sh[t + 64] + sh[t + 128] + sh[t + 192]);
}

// ---------------------------------------------------------------------------
// TAIL kernel: 256 blocks x 256 (1 block/CU — trivially co-resident), 3 grid
// barriers. Bodies = mega P7-P10 (verified rounds 4/5).
//  P7  pool + gemm2 -> z1
//  P8  dense GCN1 -> y1 + BN3 stats
//  P9  gemm3: z2 = tanh(BN3(y1)) @ W3^T
//  P10 dense GCN2 -> out + mean fold
// ---------------------------------------------------------------------------
__global__ __launch_bounds__(256) void k_tail(
    const uint32* __restrict__ aggu, const float* __restrict__ stats2r,
    const float* __restrict__ g2, const float* __restrict__ bb2,
    const float* __restrict__ w2, float* __restrict__ z1,
    const float* __restrict__ scen, const float* __restrict__ fcol,
    const float* __restrict__ b2c, float* __restrict__ y1,
    float* __restrict__ stats3r, const float* __restrict__ g3,
    const float* __restrict__ bb3, const float* __restrict__ w3,
    float* __restrict__ z2, const float* __restrict__ b3c,
    float* __restrict__ out, float* __restrict__ meanr,
    int* __restrict__ ctr, int* __restrict__ bar)
{
    __shared__ __align__(16) uchar smem[2560];
    __shared__ int flagP10;
    int t = threadIdx.x;
    int b = blockIdx.x;

    // ================= P7: pool + gemm2 =================
    {
        float* sc   = (float*)smem;             // 128
        float* sf   = (float*)(smem + 512);     // 128
        float* sh   = (float*)(smem + 1024);    // 256
        float* prow = (float*)(smem + 2048);    // 128
        int g = b;
        if (t < 128) {
            float su = 0.f, sq = 0.f;
            #pragma unroll
            for (int r = 0; r < 8; r++) {
                su += stats2r[r * 256 + t];
                sq += stats2r[r * 256 + 128 + t];
            }
            float mu  = su * (1.0f / N_NODES);
            float var = sq * (1.0f / N_NODES) - mu * mu;
            float rs  = rsqrtf(fmaxf(var, 0.f) + BN_EPS);
            float s   = rs * g2[t];
            sc[t] = s;
            sf[t] = bb2[t] - mu * s;
        }
        __syncthreads();
        int c = t & 63, grp = t >> 6;           // 4 groups x 64 rows
        float c0s = sc[2 * c], c0f = sf[2 * c], c1s = sc[2 * c + 1], c1f = sf[2 * c + 1];
        const uint32* base = aggu + (size_t)g * 256 * 64;
        float s0 = 0.f, s1 = 0.f;
        for (int r = grp * 64; r < grp * 64 + 64; r++) {
            uint32 u = base[r * 64 + c];
            s0 += ftanh(blo(u) * c0s + c0f);
            s1 += ftanh(bhi(u) * c1s + c1f);
        }
        sh[t] = s0; __syncthreads();
        if (t < 64) {
            float acc = sh[t] + sh[t + 64] + sh[t + 128] + sh[t + 192];
            prow[2 * t] = acc * (1.0f / 256.0f);
        }
        __syncthreads(); sh[t] = s1; __syncthreads();
        if (t < 64) {
            float acc = sh[t] + sh[t + 64] + sh[t + 128] + sh[t + 192];
            prow[2 * t + 1] = acc * (1.0f / 256.0f);
        }
        __syncthreads();
        float accv = 0.f;
        const float* wr = w2 + t * 128;
        for (int k = 0; k < 128; k++) accv += prow[k] * wr[k];
        z1[g * 256 + t] = accv;
    }
    gbar(bar, 256);

    // ================= P8: dense GCN1 + BN3 stats =================
    {
        float* wk = (float*)smem;
        int i = b;
        float aa = (scen[t * 256 + i] >= THRE) ? 1.0f : 0.0f;
        if (t == i) aa += 1.0f;
        wk[t] = aa * rsqrtf(fcol[t] + 1.0f);
        __syncthreads();
        float acc = 0.f;
        for (int k = 0; k < 256; k++) acc += wk[k] * z1[k * 256 + t];
        float v = rsqrtf(fcol[i] + 1.0f) * acc + b2c[t];
        y1[i * 256 + t] = v;
        float* s3 = stats3r + (i & 7) * 512;
        atomicAdd(&s3[t], v);
        atomicAdd(&s3[256 + t], v * v);
    }
    gbar(bar, 256);

    // ================= P9: gemm3 =================
    {
        float* row = (float*)smem;
        int i = b;
        {
            float s = 0.f, ss = 0.f;
            #pragma unroll
            for (int r = 0; r < 8; r++) {
                s  += stats3r[r * 512 + t];
                ss += stats3r[r * 512 + 256 + t];
            }
            float mu  = s * (1.0f / 256.0f);
            float var = ss * (1.0f / 256.0f) - mu * mu;
            float rs  = rsqrtf(fmaxf(var, 0.f) + BN_EPS);
            float scj = rs * g3[t];
            float sfj = bb3[t] - mu * scj;
            row[t] = ftanh(y1[i * 256 + t] * scj + sfj);
        }
        __syncthreads();
        if (t < 128) {
            float acc = 0.f;
            const float* wr = w3 + t * 256;
            for (int k = 0; k < 256; k++) acc += row[k] * wr[k];
            z2[i * 128 + t] = acc;
        }
    }
    gbar(bar, 256);

    // ================= P10: dense GCN2 + mean fold =================
    {
        float* wk = (float*)smem;
        int i = b;
        {
            float aa = (scen[t * 256 + i] >= THRE) ? 1.0f : 0.0f;
            if (t == i) aa += 1.0f;
            wk[t] = aa * rsqrtf(fcol[t] + 1.0f);
        }
        __syncthreads();
        if (t < 128) {
            float acc = 0.f;
            for (int k = 0; k < 256; k++) acc += wk[k] * z2[k * 128 + t];
            float v = ftanh(rsqrtf(fcol[i] + 1.0f) * acc + b3c[t]);
            out[i * 128 + t] = v;
            atomicAdd(&meanr[(i & 7) * 128 + t], v);
        }
        __syncthreads();
        if (t == 0) {
            __threadfence();
            flagP10 = (atomicAdd(ctr, 1) == 255) ? 1 : 0;
        }
        __syncthreads();
        if (flagP10) {
            __threadfence();
            if (t < 128) {
                float s = 0.f;
                #pragma unroll
                for (int r = 0; r < 8; r++) s += meanr[r * 128 + t];
                out[S_GRAPH * 128 + t] = s * (1.0f / 256.0f);
            }
        }
    }
}

// ---------------------------------------------------------------------------
extern "C" void kernel_launch(void* const* d_in, const int* in_sizes, int n_in,
                              void* d_out, int out_size, void* d_ws, size_t ws_size,
                              hipStream_t stream)
{
    const float* x        = (const float*)d_in[0];
    const float* edge_attr= (const float*)d_in[1];
    const float* scen     = (const float*)d_in[2];
    const float* wv       = (const float*)d_in[3];
    const float* bv       = (const float*)d_in[4];
    const float* wc       = (const float*)d_in[5];
    const float* bc       = (const float*)d_in[6];
    const float* w1       = (const float*)d_in[7];
    const float* b1c      = (const float*)d_in[8];
    const float* w2       = (const float*)d_in[9];
    const float* b2c      = (const float*)d_in[10];
    const float* w3       = (const float*)d_in[11];
    const float* b3c      = (const float*)d_in[12];
    const float* g1       = (const float*)d_in[13];
    const float* bb1      = (const float*)d_in[14];
    const float* g2       = (const float*)d_in[15];
    const float* bb2      = (const float*)d_in[16];
    const float* g3       = (const float*)d_in[17];
    const float* bb3      = (const float*)d_in[18];
    const int*  ei        = (const int*)d_in[20];
    const int*  nconp     = (const int*)d_in[22];
    const int*  src = ei;
    const int*  dst = ei + N_EDGES;

    float* wsf = (float*)d_ws;
    uint32*   h0u  = (uint32*)wsf;            // 16.7MB, dead after gemm1
    uint32*   aggu = (uint32*)wsf;            // alias
    uint32*   xwu  = (uint32*)(wsf + 4194304);// 16.7MB
    // zero-init block: stats, replicas, fcol, meanr, counters
    float* zb      = wsf + 8388608;
    float* stats1  = zb;                      // 512
    float* stats2r = zb + 512;                // 8*256 = 2048
    float* stats3r = zb + 2560;               // 8*512 = 4096
    float* fcol    = zb + 6656;               // 256
    float* meanr   = zb + 6912;               // 1024
    int*   ctrs    = (int*)(zb + 7936);       // 8: [1] fold, [2,3] barA, [4,5] barB
    const int ZN   = 7944;
    float* deg     = zb + ZN;                 // 65536 (dinv)
    int*   rowp    = (int*)(deg + 65536);     // 65536 (absolute padded offsets)
    int*   cnts    = rowp + 65536;            // 65536
    uint32* blkhist= (uint32*)(cnts + 65536); // 512*256 [block][bin]
    uint32* blkoff = blkhist + 131072;        // 256*512 [bin][block]
    uint32* binsz  = blkoff + 131072;         // 256
    uint2* ebin    = (uint2*)(binsz + 256 + 512); // 524288 uint2 (binned edges)
    int2*  epk     = (int2*)(ebin + 524288);  // 720896 int2 (padded CSR)
    uint32* w1bk   = (uint32*)(epk + 720896); // 8192 (32KB bf16 W1)
    float* z1      = (float*)(w1bk + 8192);   // 65536
    float* y1      = z1 + 65536;              // 65536
    float* z2      = y1 + 65536;              // 32768

    float* out = (float*)d_out;

    hipMemsetAsync(zb, 0, ZN * sizeof(float), stream);

    k_front<<<1057, 256, 0, stream>>>(x, wv, bv, wc, bc, nconp, h0u, stats1,
                                      src, dst, edge_attr, blkhist, blkoff,
                                      binsz, scen, fcol, w1, w1bk,
                                      deg, rowp, cnts, ebin, epk, &ctrs[2]);
    k_gemm1f<<<1024, 256, 0, stream>>>(h0u, w1bk, g1, bb1, stats1, (ushort16*)xwu, deg);
    k_gather<<<2048, 256, 0, stream>>>(rowp, cnts, epk, xwu, deg,
                                       (const float2*)b1c, aggu, stats2r);
    k_tail<<<256, 256, 0, stream>>>(aggu, stats2r, g2, bb2, w2, z1,
                                    scen, fcol, b2c, y1, stats3r,
                                    g3, bb3, w3, z2, b3c, out, meanr,
                                    &ctrs[1], &ctrs[4]);
}

// Round 9
// 337.083 us; speedup vs baseline: 1.6393x; 1.6303x over previous
//
#include <hip/hip_runtime.h>
#include <hip/hip_bf16.h>
#include <cstddef>

#define N_NODES 65536
#define N_EDGES 524288
#define S_GRAPH 256
#define BN_EPS 1e-5f
#define THRE 0.7f
#define BAR_STRIDE 1552   // ints per barrier instance: 32*16 l1 + 16 l2 + 64*16 gen

typedef __hip_bfloat16 bf16;
typedef unsigned int uint32;
typedef unsigned char uchar;
typedef unsigned short ushort16;
typedef __attribute__((ext_vector_type(8))) short short8;
typedef __attribute__((ext_vector_type(4))) float f32x4;

__device__ __forceinline__ float blo(uint32 u) { return __uint_as_float(u << 16); }
__device__ __forceinline__ float bhi(uint32 u) { return __uint_as_float(u & 0xffff0000u); }

__device__ __forceinline__ uint32 packbf(float a, float b)
{
    bf16 ha = __float2bfloat16(a), hb = __float2bfloat16(b);
    unsigned short ua, ub;
    __builtin_memcpy(&ua, &ha, 2); __builtin_memcpy(&ub, &hb, 2);
    return (uint32)ua | ((uint32)ub << 16);
}

// fast tanh: 1 - 2/(e^{2x}+1); |err| ~1e-6, far below bf16 rounding (2^-9)
__device__ __forceinline__ float ftanh(float x)
{
    float e = __builtin_amdgcn_exp2f(x * 2.8853900817779268f);  // 2*log2(e)
    return 1.0f - 2.0f * __builtin_amdgcn_rcpf(e + 1.0f);
}

// grid barrier v4: HIERARCHICAL arrivals. r5-r8 data: barrier cost ~80ns x
// nblk, insensitive to poll scope -> same-line arrival RMWs serialize at the
// coherent point. Fix: 32 sub-counters on separate 64B lines (b&31, ~33
// arrivals each, parallel), sub-finishers -> one 32-entry L2 counter, last
// writes a 64-replica generation array (pollers poll b&63 -> <=17/line,
// separate lines from counters). Fence discipline unchanged from R5/R6
// (verified): one release fence (L2 wb) before arrival, one acquire fence
// (L2 inv) after detection. Counters per-instance, zeroed by memset.
__device__ __forceinline__ void gbar(int* bb, int nblk)
{
    __syncthreads();
    if (threadIdx.x == 0) {
        __builtin_amdgcn_fence(__ATOMIC_RELEASE, "agent");   // wb dirty L2 once
        int b = (int)blockIdx.x;
        int r = b & 31;
        int tgt = (nblk >> 5) + ((r < (nblk & 31)) ? 1 : 0);
        if (__hip_atomic_fetch_add(&bb[r * 16], 1, __ATOMIC_RELAXED, __HIP_MEMORY_SCOPE_AGENT) == tgt - 1) {
            if (__hip_atomic_fetch_add(&bb[512], 1, __ATOMIC_RELAXED, __HIP_MEMORY_SCOPE_AGENT) == 31) {
                #pragma unroll
                for (int i = 0; i < 64; i++)
                    __hip_atomic_store(&bb[528 + i * 16], 1, __ATOMIC_RELAXED, __HIP_MEMORY_SCOPE_SYSTEM);
            }
        }
        while (!__hip_atomic_load(&bb[528 + (b & 63) * 16], __ATOMIC_RELAXED, __HIP_MEMORY_SCOPE_SYSTEM))
            __builtin_amdgcn_s_sleep(32);
        __builtin_amdgcn_fence(__ATOMIC_ACQUIRE, "agent");   // inv stale L2 once
    }
    __syncthreads();
}

// ---------------------------------------------------------------------------
// FRONT kernel: 1057 blocks x 256, 3 grid barriers. 29.7KB LDS -> 5 blk/CU
// (1280 co-resident >= 1057); __launch_bounds__(256,5) caps VGPR.
//  P1: [0..511] bin hist (bin=dst>>8) -> blkhist | [512..1023] node MLP +
//      BN1 stats | [1024..1055] fcol | [1056] W1->bf16
//  P2: per-bin scan of 512 block partials -> blkoff, binsz     [b<256]
//  P3: scatter edges into bin regions (local binsz scan)       [b<512]
//  P4: per-bin CSR build -> dinv, rowp, cnts, epk              [b<256]
// ---------------------------------------------------------------------------
__global__ __launch_bounds__(256, 5) void k_front(
    const float* __restrict__ x, const float* __restrict__ wv,
    const float* __restrict__ bv, const float* __restrict__ wc,
    const float* __restrict__ bc, const int* __restrict__ nconp,
    uint32* __restrict__ h0u, float* __restrict__ stats,
    const int* __restrict__ src, const int* __restrict__ dst,
    const float* __restrict__ ew, uint32* __restrict__ blkhist,
    uint32* __restrict__ blkoff, uint32* __restrict__ binsz,
    const float* __restrict__ scen, float* __restrict__ fcol,
    const float* __restrict__ w1f, uint32* __restrict__ w1bk,
    float* __restrict__ dinv, int* __restrict__ rowp, int* __restrict__ cnts,
    uint2* __restrict__ ebin, int2* __restrict__ epk, int* __restrict__ bar)
{
    __shared__ __align__(16) uchar smem[29696];
    int t = threadIdx.x;
    int b = blockIdx.x;

    // ================= P1 =================
    if (b < 512) {                                // ---- bin histogram ----
        uint32* bh = (uint32*)smem;
        bh[t] = 0;
        __syncthreads();
        int e0 = b * 1024 + t * 4;
        int4 d4 = *(const int4*)(dst + e0);
        atomicAdd(&bh[d4.x >> 8], 1u);
        atomicAdd(&bh[d4.y >> 8], 1u);
        atomicAdd(&bh[d4.z >> 8], 1u);
        atomicAdd(&bh[d4.w >> 8], 1u);
        __syncthreads();
        blkhist[b * 256 + t] = bh[t];
    } else if (b < 1024) {                        // ---- node MLP ----
        float* xs = (float*)smem;                 // 768 floats
        float* sh = (float*)(smem + 3072);        // 256 floats
        int n0 = (b - 512) * 128;
        if (t < 192) ((float4*)xs)[t] = ((const float4*)(x + (size_t)n0 * 6))[t];
        __syncthreads();

        int nc = *nconp;
        int lane = t & 63, wave = t >> 6;
        int j0 = 2 * lane;
        const float2* wv2 = (const float2*)wv;
        float2 wa0 = wv2[j0 * 3], wa1 = wv2[j0 * 3 + 1], wa2 = wv2[j0 * 3 + 2];
        float2 wb0 = wv2[j0 * 3 + 3], wb1 = wv2[j0 * 3 + 4], wb2 = wv2[j0 * 3 + 5];
        float wc0 = wc[j0], wc1 = wc[j0 + 1], bc0 = bc[j0], bc1 = bc[j0 + 1];
        float bv0 = bv[j0], bv1 = bv[j0 + 1];

        float s0 = 0.f, ss0 = 0.f, s1 = 0.f, ss1 = 0.f;
        #pragma unroll 4
        for (int m = 0; m < 32; m++) {
            int ln = wave * 32 + m;               // local node, wave-uniform
            int n = n0 + ln;
            const float* xr = &xs[ln * 6];
            float a0, a1;
            if (n < nc) {
                float xv = xr[0];
                a0 = xv * wc0 + bc0; a1 = xv * wc1 + bc1;
            } else {
                float x0 = xr[0], x1 = xr[1], x2 = xr[2], x3 = xr[3], x4 = xr[4], x5 = xr[5];
                a0 = bv0 + x0 * wa0.x + x1 * wa0.y + x2 * wa1.x + x3 * wa1.y + x4 * wa2.x + x5 * wa2.y;
                a1 = bv1 + x0 * wb0.x + x1 * wb0.y + x2 * wb1.x + x3 * wb1.y + x4 * wb2.x + x5 * wb2.y;
            }
            uint32 pk = packbf(ftanh(a0), ftanh(a1));
            h0u[(size_t)n * 64 + lane] = pk;
            float v0 = blo(pk), v1 = bhi(pk);     // stats on rounded values
            s0 += v0; ss0 += v0 * v0; s1 += v1; ss1 += v1 * v1;
        }
        sh[t] = s0; __syncthreads();
        if (t < 64) atomicAdd(&stats[2 * t], sh[t] + sh[t + 64] + sh[t + 128] + sh[t + 192]);
        __syncthreads(); sh[t] = s1; __syncthreads();
        if (t < 64) atomicAdd(&stats[2 * t + 1], sh[t] + sh[t + 64] + sh[t + 128] + sh[t + 192]);
        __syncthreads(); sh[t] = ss0; __syncthreads();
        if (t < 64) atomicAdd(&stats[128 + 2 * t], sh[t] + sh[t + 64] + sh[t + 128] + sh[t + 192]);
        __syncthreads(); sh[t] = ss1; __syncthreads();
        if (t < 64) atomicAdd(&stats[128 + 2 * t + 1], sh[t] + sh[t + 64] + sh[t + 128] + sh[t + 192]);
    } else if (b < 1056) {                        // ---- dense col sums ----
        int r0 = (b - 1024) * 8;
        float s = 0.f;
        for (int r = r0; r < r0 + 8; r++)
            s += (scen[r * 256 + t] >= THRE) ? 1.0f : 0.0f;
        atomicAdd(&fcol[t], s);
    } else {                                      // ---- W1 -> bf16 pack ----
        const float4* w4 = (const float4*)w1f;
        uint2* wo = (uint2*)w1bk;
        #pragma unroll
        for (int it = 0; it < 16; it++) {
            int fi = it * 256 + t;                // 4096 float4
            float4 w = w4[fi];
            wo[fi] = make_uint2(packbf(w.x, w.y), packbf(w.z, w.w));
        }
    }
    gbar(bar, 1057);

    // ================= P2: per-bin scan of block partials =================
    if (b < 256) {
        uint32* v  = (uint32*)smem;               // 512
        uint32* ps = (uint32*)(smem + 2048);      // 256
        int g = b;
        v[t]       = blkhist[t * 256 + g];
        v[t + 256] = blkhist[(t + 256) * 256 + g];
        __syncthreads();
        uint32 a0 = v[2 * t], a1 = v[2 * t + 1];
        ps[t] = a0 + a1; __syncthreads();
        for (int o = 1; o < 256; o <<= 1) {
            uint32 u = (t >= o) ? ps[t - o] : 0;
            __syncthreads();
            ps[t] += u;
            __syncthreads();
        }
        uint32 ex = ps[t] - (a0 + a1);            // exclusive over block pairs
        ((uint2*)blkoff)[g * 256 + t] = make_uint2(ex, ex + a0);
        if (t == 255) binsz[g] = ps[255];
    }
    gbar(bar + BAR_STRIDE, 1057);

    // ================= P3: scatter edges into bins =================
    if (b < 512) {
        uint32* ps = (uint32*)smem;               // 256
        uint32* bo = (uint32*)(smem + 1024);      // 256
        uint32* bh = (uint32*)(smem + 2048);      // 256
        uint32 s = binsz[t];
        ps[t] = s; __syncthreads();
        for (int o = 1; o < 256; o <<= 1) {
            uint32 u = (t >= o) ? ps[t - o] : 0;
            __syncthreads();
            ps[t] += u;
            __syncthreads();
        }
        bo[t] = (ps[t] - s) + blkoff[t * 512 + b];
        bh[t] = 0;
        __syncthreads();
        int e0 = b * 1024 + t * 4;
        int4 d4 = *(const int4*)(dst + e0);
        int4 s4 = *(const int4*)(src + e0);
        float4 w4 = *(const float4*)(ew + e0);
        int bin; uint32 r;
        bin = d4.x >> 8; r = atomicAdd(&bh[bin], 1u);
        ebin[bo[bin] + r] = make_uint2((uint32)s4.x | ((uint32)(d4.x & 255) << 16), __float_as_uint(w4.x));
        bin = d4.y >> 8; r = atomicAdd(&bh[bin], 1u);
        ebin[bo[bin] + r] = make_uint2((uint32)s4.y | ((uint32)(d4.y & 255) << 16), __float_as_uint(w4.y));
        bin = d4.z >> 8; r = atomicAdd(&bh[bin], 1u);
        ebin[bo[bin] + r] = make_uint2((uint32)s4.z | ((uint32)(d4.z & 255) << 16), __float_as_uint(w4.z));
        bin = d4.w >> 8; r = atomicAdd(&bh[bin], 1u);
        ebin[bo[bin] + r] = make_uint2((uint32)s4.w | ((uint32)(d4.w & 255) << 16), __float_as_uint(w4.w));
    }
    gbar(bar + 2 * BAR_STRIDE, 1057);

    // ================= P4: per-bin CSR build =================
    if (b < 256) {
        uint2* es    = (uint2*)smem;              // 24576B
        uint32* hist = (uint32*)(smem + 24576);   // 1024B
        int* sscan   = (int*)(smem + 25600);      // 1024B
        int* rloc    = (int*)(smem + 26624);      // 1024B
        float* dlv   = (float*)(smem + 27648);    // 1024B
        uint32* ubl  = (uint32*)(smem + 28672);   // 1024B
        int g = b;
        {
            uint32 s = binsz[t];
            sscan[t] = (int)s; __syncthreads();
            for (int o = 1; o < 256; o <<= 1) {
                int u = (t >= o) ? sscan[t - o] : 0;
                __syncthreads();
                sscan[t] += u;
                __syncthreads();
            }
            ubl[t] = (uint32)sscan[t] - s;
        }
        __syncthreads();
        int start = (int)ubl[g];
        int sz = min((int)binsz[g], 3072);
        int pb = start + g * 768;
        hist[t] = 0;
        __syncthreads();
        for (int i2 = t; i2 < sz; i2 += 256) {    // load + rank in one pass
            uint2 e = ebin[start + i2];
            int dl = (e.x >> 16) & 255;
            uint32 wfix = __float2uint_rn(__uint_as_float(e.y) * 262144.0f);
            uint32 h = atomicAdd(&hist[dl], (1u << 24) | wfix);
            e.x |= (h >> 24) << 24;               // rank (u8) into top byte
            es[i2] = e;
        }
        __syncthreads();
        uint32 hv = hist[t];
        int cnt = (int)(hv >> 24);
        float di = rsqrtf((float)(hv & 0xFFFFFFu) * 3.814697265625e-6f + 1.0f);
        dlv[t] = di;
        dinv[g * 256 + t] = di;
        cnts[g * 256 + t] = cnt;
        int pcnt = (cnt + 3) & ~3;
        sscan[t] = pcnt; __syncthreads();
        for (int o = 1; o < 256; o <<= 1) {
            int u = (t >= o) ? sscan[t - o] : 0;
            __syncthreads();
            sscan[t] += u;
            __syncthreads();
        }
        int rl = sscan[t] - pcnt;
        rloc[t] = rl;
        rowp[g * 256 + t] = pb + rl;
        __syncthreads();
        for (int i2 = t; i2 < sz; i2 += 256) {
            uint2 e = es[i2];
            int s2 = (int)(e.x & 0xFFFFu);
            int dl = (int)((e.x >> 16) & 255u);
            int r  = (int)(e.x >> 24);
            float w = __uint_as_float(e.y) * dlv[dl];
            epk[pb + rloc[dl] + r] = make_int2(s2, __float_as_int(w));
        }
        int basep = pb + rl;
        for (int q = cnt; q < pcnt; q++) epk[basep + q] = make_int2(g * 256 + t, 0);
    }
}

// ---------------------------------------------------------------------------
// GEMM1: xw = dinv ⊙ (BN1(h0) @ W1^T) via MFMA bf16. Unchanged (occupancy-
// critical: 53KB LDS, kept standalone).
// ---------------------------------------------------------------------------
__global__ __launch_bounds__(256) void k_gemm1f(
    const uint32* __restrict__ h0u, const uint32* __restrict__ w1bk,
    const float* __restrict__ g1, const float* __restrict__ bb1,
    const float* __restrict__ stats, ushort16* __restrict__ xws,
    const float* __restrict__ dinv)
{
    __shared__ short hn_s[64 * 136];    // bf16 bits, row-major, stride 136 (2-way max)
    __shared__ short w_s[128 * 136];
    __shared__ float sc[128], sf[128];
    int t = threadIdx.x;
    int blk = blockIdx.x;
    int row0 = blk * 64;

    if (t < 128) {
        float mu  = stats[t] * (1.0f / N_NODES);
        float var = stats[128 + t] * (1.0f / N_NODES) - mu * mu;
        float rs  = rsqrtf(fmaxf(var, 0.f) + BN_EPS);
        float s   = rs * g1[t];
        sc[t] = s;
        sf[t] = bb1[t] - mu * s;
    }
    __syncthreads();

    const uint4* h4 = (const uint4*)(h0u + (size_t)row0 * 64);
    #pragma unroll
    for (int it = 0; it < 4; it++) {
        int slot = it * 256 + t;
        int r = slot >> 4, k0 = (slot & 15) * 8;
        uint4 u = h4[slot];
        uint32 ua[4] = {u.x, u.y, u.z, u.w};
        uint32 o[4];
        #pragma unroll
        for (int m = 0; m < 4; m++) {
            int k = k0 + 2 * m;
            o[m] = packbf(blo(ua[m]) * sc[k] + sf[k], bhi(ua[m]) * sc[k + 1] + sf[k + 1]);
        }
        *(uint4*)&hn_s[r * 136 + k0] = make_uint4(o[0], o[1], o[2], o[3]);
    }
    const uint4* wv4 = (const uint4*)w1bk;
    #pragma unroll
    for (int it = 0; it < 8; it++) {
        int s2 = it * 256 + t;              // 2048 uint4 (8 bf16 each)
        int c = s2 >> 4, k0 = (s2 & 15) * 8;
        *(uint4*)&w_s[c * 136 + k0] = wv4[s2];
    }
    __syncthreads();

    int lane = t & 63, wave = t >> 6;
    int m16 = lane & 15, kh = lane >> 4;
    int mbase = wave * 16;
    f32x4 acc[8] = {};
    #pragma unroll
    for (int ks = 0; ks < 4; ks++) {
        short8 a = *(const short8*)&hn_s[(mbase + m16) * 136 + ks * 32 + kh * 8];
        #pragma unroll
        for (int ct = 0; ct < 8; ct++) {
            short8 bfr = *(const short8*)&w_s[(ct * 16 + m16) * 136 + ks * 32 + kh * 8];
            acc[ct] = __builtin_amdgcn_mfma_f32_16x16x32_bf16(a, bfr, acc[ct], 0, 0, 0);
        }
    }
    float dvr[4];
    #pragma unroll
    for (int r = 0; r < 4; r++) dvr[r] = dinv[row0 + mbase + kh * 4 + r];
    #pragma unroll
    for (int ct = 0; ct < 8; ct++) {
        int col = ct * 16 + m16;
        #pragma unroll
        for (int r = 0; r < 4; r++) {
            int row = mbase + kh * 4 + r;
            bf16 hv = __float2bfloat16(acc[ct][r] * dvr[r]);
            unsigned short us; __builtin_memcpy(&us, &hv, 2);
            xws[(size_t)(row0 + row) * 128 + col] = us;
        }
    }
}

// ---------------------------------------------------------------------------
// GATHER + fused BN2 stats. Unchanged (occupancy-critical: latency-bound,
// needs 32 waves/CU, kept standalone). 2048 blocks x 256, 32 nodes/block.
// ---------------------------------------------------------------------------
__global__ __launch_bounds__(256) void k_gather(
    const int* __restrict__ rowp, const int* __restrict__ cnts,
    const int2* __restrict__ epk, const uint32* __restrict__ xwu,
    const float* __restrict__ dinv, const float2* __restrict__ b1c2,
    uint32* __restrict__ aggu, float* __restrict__ stats2r)
{
    __shared__ float sh[256];
    int t = threadIdx.x, b = blockIdx.x;
    int lane = t & 63, wave = t >> 6;
    float2 bb = b1c2[lane];
    float s0 = 0.f, ss0 = 0.f, s1 = 0.f, ss1 = 0.f;
    for (int it = 0; it < 8; it++) {
        int n = b * 32 + it * 4 + wave;
        int st = rowp[n];
        int pcnt = (cnts[n] + 3) & ~3;
        float di = dinv[n];
        uint32 u0 = xwu[(size_t)n * 64 + lane];
        float ax = di * blo(u0) + bb.x;
        float ay = di * bhi(u0) + bb.y;
        int en = st + pcnt;
        for (int p = st; p < en; p += 4) {
            int2 q0 = epk[p], q1 = epk[p + 1], q2 = epk[p + 2], q3 = epk[p + 3];
            uint32 v0 = xwu[(size_t)q0.x * 64 + lane];
            uint32 v1 = xwu[(size_t)q1.x * 64 + lane];
            uint32 v2 = xwu[(size_t)q2.x * 64 + lane];
            uint32 v3 = xwu[(size_t)q3.x * 64 + lane];
            float w0 = __int_as_float(q0.y), w1 = __int_as_float(q1.y);
            float w2 = __int_as_float(q2.y), w3 = __int_as_float(q3.y);
            ax += w0 * blo(v0) + w1 * blo(v1) + w2 * blo(v2) + w3 * blo(v3);
            ay += w0 * bhi(v0) + w1 * bhi(v1) + w2 * bhi(v2) + w3 * bhi(v3);
        }
        uint32 pk = packbf(ax, ay);
        aggu[(size_t)n * 64 + lane] = pk;
        float v0 = blo(pk), v1 = bhi(pk);
        s0 += v0; ss0 += v0 * v0; s1 += v1; ss1 += v1 * v1;
    }
    float* st2 = stats2r + (b & 7) * 256;
    sh[t] = s0; __syncthreads();
    if (t < 64) atomicAdd(&st2[2 * t], sh[t] + sh[t + 64] + sh[t + 128] + sh[t + 192]);
    __syncthreads(); sh[t] = s1; __syncthreads();
    if (t < 64) atomicAdd(&st2[2 * t + 1], sh[t] + sh[t + 64] + sh[t + 128] + sh[t + 192]);
    __syncthreads(); sh[t] = ss0; __syncthreads();
    if (t < 64) atomicAdd(&st2[128 + 2 * t], sh[t] + sh[t + 64] + sh[t + 128] + sh[t + 192]);
    __syncthreads(); sh[t] = ss1; __syncthreads();
    if (t < 64) atomicAdd(&st2[128 + 2 * t + 1], sh[t] + sh[t + 64] + sh[t + 128] + sh[t + 192]);
}

// ---------------------------------------------------------------------------
// TAIL kernel: 256 blocks x 256 (1 block/CU — trivially co-resident), 4 grid
// barriers (4th replaces the old 256-RMW single-line fold counter).
//  P7  pool + gemm2 -> z1
//  P8  dense GCN1 -> y1 + BN3 stats
//  P9  gemm3: z2 = tanh(BN3(y1)) @ W3^T
//  P10 dense GCN2 -> out; barrier; block 0 folds mean replicas
// ---------------------------------------------------------------------------
__global__ __launch_bounds__(256) void k_tail(
    const uint32* __restrict__ aggu, const float* __restrict__ stats2r,
    const float* __restrict__ g2, const float* __restrict__ bb2,
    const float* __restrict__ w2, float* __restrict__ z1,
    const float* __restrict__ scen, const float* __restrict__ fcol,
    const float* __restrict__ b2c, float* __restrict__ y1,
    float* __restrict__ stats3r, const float* __restrict__ g3,
    const float* __restrict__ bb3, const float* __restrict__ w3,
    float* __restrict__ z2, const float* __restrict__ b3c,
    float* __restrict__ out, float* __restrict__ meanr,
    int* __restrict__ bar)
{
    __shared__ __align__(16) uchar smem[2560];
    int t = threadIdx.x;
    int b = blockIdx.x;

    // ================= P7: pool + gemm2 =================
    {
        float* sc   = (float*)smem;             // 128
        float* sf   = (float*)(smem + 512);     // 128
        float* sh   = (float*)(smem + 1024);    // 256
        float* prow = (float*)(smem + 2048);    // 128
        int g = b;
        if (t < 128) {
            float su = 0.f, sq = 0.f;
            #pragma unroll
            for (int r = 0; r < 8; r++) {
                su += stats2r[r * 256 + t];
                sq += stats2r[r * 256 + 128 + t];
            }
            float mu  = su * (1.0f / N_NODES);
            float var = sq * (1.0f / N_NODES) - mu * mu;
            float rs  = rsqrtf(fmaxf(var, 0.f) + BN_EPS);
            float s   = rs * g2[t];
            sc[t] = s;
            sf[t] = bb2[t] - mu * s;
        }
        __syncthreads();
        int c = t & 63, grp = t >> 6;           // 4 groups x 64 rows
        float c0s = sc[2 * c], c0f = sf[2 * c], c1s = sc[2 * c + 1], c1f = sf[2 * c + 1];
        const uint32* base = aggu + (size_t)g * 256 * 64;
        float s0 = 0.f, s1 = 0.f;
        for (int r = grp * 64; r < grp * 64 + 64; r++) {
            uint32 u = base[r * 64 + c];
            s0 += ftanh(blo(u) * c0s + c0f);
            s1 += ftanh(bhi(u) * c1s + c1f);
        }
        sh[t] = s0; __syncthreads();
        if (t < 64) {
            float acc = sh[t] + sh[t + 64] + sh[t + 128] + sh[t + 192];
            prow[2 * t] = acc * (1.0f / 256.0f);
        }
        __syncthreads(); sh[t] = s1; __syncthreads();
        if (t < 64) {
            float acc = sh[t] + sh[t + 64] + sh[t + 128] + sh[t + 192];
            prow[2 * t + 1] = acc * (1.0f / 256.0f);
        }
        __syncthreads();
        float accv = 0.f;
        const float* wr = w2 + t * 128;
        for (int k = 0; k < 128; k++) accv += prow[k] * wr[k];
        z1[g * 256 + t] = accv;
    }
    gbar(bar, 256);

    // ================= P8: dense GCN1 + BN3 stats =================
    {
        float* wk = (float*)smem;
        int i = b;
        float aa = (scen[t * 256 + i] >= THRE) ? 1.0f : 0.0f;
        if (t == i) aa += 1.0f;
        wk[t] = aa * rsqrtf(fcol[t] + 1.0f);
        __syncthreads();
        float acc = 0.f;
        for (int k = 0; k < 256; k++) acc += wk[k] * z1[k * 256 + t];
        float v = rsqrtf(fcol[i] + 1.0f) * acc + b2c[t];
        y1[i * 256 + t] = v;
        float* s3 = stats3r + (i & 7) * 512;
        atomicAdd(&s3[t], v);
        atomicAdd(&s3[256 + t], v * v);
    }
    gbar(bar + BAR_STRIDE, 256);

    // ================= P9: gemm3 =================
    {
        float* row = (float*)smem;
        int i = b;
        {
            float s = 0.f, ss = 0.f;
            #pragma unroll
            for (int r = 0; r < 8; r++) {
                s  += stats3r[r * 512 + t];
                ss += stats3r[r * 512 + 256 + t];
            }
            float mu  = s * (1.0f / 256.0f);
            float var = ss * (1.0f / 256.0f) - mu * mu;
            float rs  = rsqrtf(fmaxf(var, 0.f) + BN_EPS);
            float scj = rs * g3[t];
            float sfj = bb3[t] - mu * scj;
            row[t] = ftanh(y1[i * 256 + t] * scj + sfj);
        }
        __syncthreads();
        if (t < 128) {
            float acc = 0.f;
            const float* wr = w3 + t * 256;
            for (int k = 0; k < 256; k++) acc += row[k] * wr[k];
            z2[i * 128 + t] = acc;
        }
    }
    gbar(bar + 2 * BAR_STRIDE, 256);

    // ================= P10: dense GCN2; barrier; block0 mean fold =========
    {
        float* wk = (float*)smem;
        int i = b;
        {
            float aa = (scen[t * 256 + i] >= THRE) ? 1.0f : 0.0f;
            if (t == i) aa += 1.0f;
            wk[t] = aa * rsqrtf(fcol[t] + 1.0f);
        }
        __syncthreads();
        if (t < 128) {
            float acc = 0.f;
            for (int k = 0; k < 256; k++) acc += wk[k] * z2[k * 128 + t];
            float v = ftanh(rsqrtf(fcol[i] + 1.0f) * acc + b3c[t]);
            out[i * 128 + t] = v;
            atomicAdd(&meanr[(i & 7) * 128 + t], v);
        }
    }
    gbar(bar + 3 * BAR_STRIDE, 256);
    if (b == 0 && t < 128) {
        float s = 0.f;
        #pragma unroll
        for (int r = 0; r < 8; r++) s += meanr[r * 128 + t];
        out[S_GRAPH * 128 + t] = s * (1.0f / 256.0f);
    }
}

// ---------------------------------------------------------------------------
extern "C" void kernel_launch(void* const* d_in, const int* in_sizes, int n_in,
                              void* d_out, int out_size, void* d_ws, size_t ws_size,
                              hipStream_t stream)
{
    const float* x        = (const float*)d_in[0];
    const float* edge_attr= (const float*)d_in[1];
    const float* scen     = (const float*)d_in[2];
    const float* wv       = (const float*)d_in[3];
    const float* bv       = (const float*)d_in[4];
    const float* wc       = (const float*)d_in[5];
    const float* bc       = (const float*)d_in[6];
    const float* w1       = (const float*)d_in[7];
    const float* b1c      = (const float*)d_in[8];
    const float* w2       = (const float*)d_in[9];
    const float* b2c      = (const float*)d_in[10];
    const float* w3       = (const float*)d_in[11];
    const float* b3c      = (const float*)d_in[12];
    const float* g1       = (const float*)d_in[13];
    const float* bb1      = (const float*)d_in[14];
    const float* g2       = (const float*)d_in[15];
    const float* bb2      = (const float*)d_in[16];
    const float* g3       = (const float*)d_in[17];
    const float* bb3      = (const float*)d_in[18];
    const int*  ei        = (const int*)d_in[20];
    const int*  nconp     = (const int*)d_in[22];
    const int*  src = ei;
    const int*  dst = ei + N_EDGES;

    float* wsf = (float*)d_ws;
    uint32*   h0u  = (uint32*)wsf;            // 16.7MB, dead after gemm1
    uint32*   aggu = (uint32*)wsf;            // alias
    uint32*   xwu  = (uint32*)(wsf + 4194304);// 16.7MB
    // zero-init block: stats, replicas, fcol, meanr, barrier instances
    float* zb      = wsf + 8388608;
    float* stats1  = zb;                      // 512
    float* stats2r = zb + 512;                // 8*256 = 2048
    float* stats3r = zb + 2560;               // 8*512 = 4096
    float* fcol    = zb + 6656;               // 256
    float* meanr   = zb + 6912;               // 1024
    int*   bars    = (int*)(zb + 7952);       // 7 barrier instances x 1552 ints
    const int ZN   = 7952 + 7 * BAR_STRIDE;   // = 18816
    float* deg     = zb + ZN;                 // 65536 (dinv)
    int*   rowp    = (int*)(deg + 65536);     // 65536 (absolute padded offsets)
    int*   cnts    = rowp + 65536;            // 65536
    uint32* blkhist= (uint32*)(cnts + 65536); // 512*256 [block][bin]
    uint32* blkoff = blkhist + 131072;        // 256*512 [bin][block]
    uint32* binsz  = blkoff + 131072;         // 256
    uint2* ebin    = (uint2*)(binsz + 256 + 512); // 524288 uint2 (binned edges)
    int2*  epk     = (int2*)(ebin + 524288);  // 720896 int2 (padded CSR)
    uint32* w1bk   = (uint32*)(epk + 720896); // 8192 (32KB bf16 W1)
    float* z1      = (float*)(w1bk + 8192);   // 65536
    float* y1      = z1 + 65536;              // 65536
    float* z2      = y1 + 65536;              // 32768

    float* out = (float*)d_out;

    hipMemsetAsync(zb, 0, ZN * sizeof(float), stream);

    k_front<<<1057, 256, 0, stream>>>(x, wv, bv, wc, bc, nconp, h0u, stats1,
                                      src, dst, edge_attr, blkhist, blkoff,
                                      binsz, scen, fcol, w1, w1bk,
                                      deg, rowp, cnts, ebin, epk, bars);
    k_gemm1f<<<1024, 256, 0, stream>>>(h0u, w1bk, g1, bb1, stats1, (ushort16*)xwu, deg);
    k_gather<<<2048, 256, 0, stream>>>(rowp, cnts, epk, xwu, deg,
                                       (const float2*)b1c, aggu, stats2r);
    k_tail<<<256, 256, 0, stream>>>(aggu, stats2r, g2, bb2, w2, z1,
                                    scen, fcol, b2c, y1, stats3r,
                                    g3, bb3, w3, z2, b3c, out, meanr,
                                    bars + 3 * BAR_STRIDE);
}

// Round 10
// 238.808 us; speedup vs baseline: 2.3139x; 1.4115x over previous
//
#include <hip/hip_runtime.h>
#include <hip/hip_bf16.h>
#include <cstddef>

#define N_NODES 65536
#define N_EDGES 524288
#define S_GRAPH 256
#define BN_EPS 1e-5f
#define THRE 0.7f

typedef __hip_bfloat16 bf16;
typedef unsigned int uint32;
typedef unsigned char uchar;
typedef unsigned short ushort16;
typedef __attribute__((ext_vector_type(8))) short short8;
typedef __attribute__((ext_vector_type(4))) float f32x4;

__device__ __forceinline__ float blo(uint32 u) { return __uint_as_float(u << 16); }
__device__ __forceinline__ float bhi(uint32 u) { return __uint_as_float(u & 0xffff0000u); }

__device__ __forceinline__ uint32 packbf(float a, float b)
{
    bf16 ha = __float2bfloat16(a), hb = __float2bfloat16(b);
    unsigned short ua, ub;
    __builtin_memcpy(&ua, &ha, 2); __builtin_memcpy(&ub, &hb, 2);
    return (uint32)ua | ((uint32)ub << 16);
}

// fast tanh: 1 - 2/(e^{2x}+1); |err| ~1e-6, far below bf16 rounding (2^-9)
__device__ __forceinline__ float ftanh(float x)
{
    float e = __builtin_amdgcn_exp2f(x * 2.8853900817779268f);  // 2*log2(e)
    return 1.0f - 2.0f * __builtin_amdgcn_rcpf(e + 1.0f);
}

// ---------------------------------------------------------------------------
// 1) Fused front-end, 1057 blocks. NO memset needed: all accumulators are
//    either non-atomic (stats1 partials, fcol) or zeroed here for later
//    kernels (stats2r/stats3r/meanr/ctrs — consumed only downstream).
//    [0..511]    coarse bin histogram (bin = dst>>8) -> blkhist
//    [512..1023] node MLP -> bf16 h0 + BN1 partial stats (non-atomic)
//    [1024]      fcol: full dense adjacency column sums (single block)
//    [1056]      W1 fp32->bf16 pack + zero downstream accumulators
// ---------------------------------------------------------------------------
__global__ __launch_bounds__(256) void k_mlp_hist(
    const float* __restrict__ x, const float* __restrict__ wv,
    const float* __restrict__ bv, const float* __restrict__ wc,
    const float* __restrict__ bc, const int* __restrict__ nconp,
    uint32* __restrict__ h0u, float* __restrict__ pstat,
    const int* __restrict__ dst, uint32* __restrict__ blkhist,
    const float* __restrict__ scen, float* __restrict__ fcol,
    const float* __restrict__ w1f, uint32* __restrict__ w1bk,
    float* __restrict__ zacc, int* __restrict__ ctrs)
{
    __shared__ float xs[128 * 6];
    __shared__ float sh[256];
    __shared__ uint32 bh[256];
    int t = threadIdx.x;
    int b = blockIdx.x;
    if (b < 512) {                                // ---- bin histogram ----
        bh[t] = 0;
        __syncthreads();
        int e0 = b * 1024 + t * 4;
        int4 d4 = *(const int4*)(dst + e0);
        atomicAdd(&bh[d4.x >> 8], 1u);
        atomicAdd(&bh[d4.y >> 8], 1u);
        atomicAdd(&bh[d4.z >> 8], 1u);
        atomicAdd(&bh[d4.w >> 8], 1u);
        __syncthreads();
        blkhist[b * 256 + t] = bh[t];
        return;
    }
    if (b >= 1024) {
        if (b == 1024) {                          // ---- fcol, non-atomic ----
            float s = 0.f;
            for (int r = 0; r < 256; r++)
                s += (scen[r * 256 + t] >= THRE) ? 1.0f : 0.0f;
            fcol[t] = s;
        } else if (b == 1056) {                   // ---- W1 pack + zeroing ----
            const float4* w4 = (const float4*)w1f;
            uint2* wo = (uint2*)w1bk;
            #pragma unroll
            for (int it = 0; it < 16; it++) {
                int fi = it * 256 + t;            // 4096 float4
                float4 w = w4[fi];
                wo[fi] = make_uint2(packbf(w.x, w.y), packbf(w.z, w.w));
            }
            // zero stats2r(2048) + stats3r(4096) + meanr(1024) = 7168 floats
            for (int i = t; i < 7168; i += 256) zacc[i] = 0.f;
            if (t < 8) ctrs[t] = 0;
        }
        return;
    }
    // ---- node MLP path: block handles 128 nodes ----
    int n0 = (b - 512) * 128;
    if (t < 192) ((float4*)xs)[t] = ((const float4*)(x + (size_t)n0 * 6))[t];
    __syncthreads();

    int nc = *nconp;
    int lane = t & 63, wave = t >> 6;
    int j0 = 2 * lane;
    const float2* wv2 = (const float2*)wv;
    float2 wa0 = wv2[j0 * 3], wa1 = wv2[j0 * 3 + 1], wa2 = wv2[j0 * 3 + 2];
    float2 wb0 = wv2[j0 * 3 + 3], wb1 = wv2[j0 * 3 + 4], wb2 = wv2[j0 * 3 + 5];
    float wc0 = wc[j0], wc1 = wc[j0 + 1], bc0 = bc[j0], bc1 = bc[j0 + 1];
    float bv0 = bv[j0], bv1 = bv[j0 + 1];

    float s0 = 0.f, ss0 = 0.f, s1 = 0.f, ss1 = 0.f;
    #pragma unroll 4
    for (int m = 0; m < 32; m++) {
        int ln = wave * 32 + m;                   // local node, wave-uniform
        int n = n0 + ln;
        const float* xr = &xs[ln * 6];
        float a0, a1;
        if (n < nc) {
            float xv = xr[0];
            a0 = xv * wc0 + bc0; a1 = xv * wc1 + bc1;
        } else {
            float x0 = xr[0], x1 = xr[1], x2 = xr[2], x3 = xr[3], x4 = xr[4], x5 = xr[5];
            a0 = bv0 + x0 * wa0.x + x1 * wa0.y + x2 * wa1.x + x3 * wa1.y + x4 * wa2.x + x5 * wa2.y;
            a1 = bv1 + x0 * wb0.x + x1 * wb0.y + x2 * wb1.x + x3 * wb1.y + x4 * wb2.x + x5 * wb2.y;
        }
        uint32 pk = packbf(ftanh(a0), ftanh(a1));
        h0u[(size_t)n * 64 + lane] = pk;
        float v0 = blo(pk), v1 = bhi(pk);         // stats on rounded values
        s0 += v0; ss0 += v0 * v0; s1 += v1; ss1 += v1 * v1;
    }
    // per-block partial stats (non-atomic): layout [0..127]=sums, [128..255]=sqs
    float* pst = pstat + (size_t)(b - 512) * 256;
    sh[t] = s0; __syncthreads();
    if (t < 64) pst[2 * t] = sh[t] + sh[t + 64] + sh[t + 128] + sh[t + 192];
    __syncthreads(); sh[t] = s1; __syncthreads();
    if (t < 64) pst[2 * t + 1] = sh[t] + sh[t + 64] + sh[t + 128] + sh[t + 192];
    __syncthreads(); sh[t] = ss0; __syncthreads();
    if (t < 64) pst[128 + 2 * t] = sh[t] + sh[t + 64] + sh[t + 128] + sh[t + 192];
    __syncthreads(); sh[t] = ss1; __syncthreads();
    if (t < 64) pst[128 + 2 * t + 1] = sh[t] + sh[t + 64] + sh[t + 128] + sh[t + 192];
}

// ---------------------------------------------------------------------------
// 2) 257 blocks. [g<256]: per-bin scan of the 512 block-partials ->
//    blkoff[bin][block] + bin totals; last-finishing block scans bin totals
//    into ubase/pbase. [g==256]: reduce the 512 stats1 partials (coalesced).
// ---------------------------------------------------------------------------
__global__ __launch_bounds__(256) void k_binscan(
    const uint32* __restrict__ blkhist, uint32* __restrict__ blkoff,
    uint32* __restrict__ binsz, uint32* __restrict__ ubase,
    uint32* __restrict__ pbase, const float* __restrict__ pstat,
    float* __restrict__ stats, int* __restrict__ ctr)
{
    __shared__ uint32 v[512];
    __shared__ uint32 ps[256];
    __shared__ int flag;
    int g = blockIdx.x, t = threadIdx.x;
    if (g == 256) {                               // ---- stats1 reduce ----
        float acc = 0.f;
        for (int j = 0; j < 512; j++) acc += pstat[j * 256 + t];
        stats[t] = acc;
        return;
    }
    v[t]       = blkhist[t * 256 + g];
    v[t + 256] = blkhist[(t + 256) * 256 + g];
    __syncthreads();
    uint32 a0 = v[2 * t], a1 = v[2 * t + 1];
    ps[t] = a0 + a1; __syncthreads();
    for (int o = 1; o < 256; o <<= 1) {
        uint32 u = (t >= o) ? ps[t - o] : 0;
        __syncthreads();
        ps[t] += u;
        __syncthreads();
    }
    uint32 ex = ps[t] - (a0 + a1);                // exclusive over block pairs
    ((uint2*)blkoff)[g * 256 + t] = make_uint2(ex, ex + a0);
    if (t == 255) atomicExch((int*)&binsz[g], (int)ps[255]);
    __syncthreads();
    if (t == 0) {
        __threadfence();
        flag = (atomicAdd(ctr, 1) == 255) ? 1 : 0;
    }
    __syncthreads();
    if (flag) {
        __threadfence();
        uint32 s = binsz[t];
        ps[t] = s; __syncthreads();
        for (int o = 1; o < 256; o <<= 1) {
            uint32 u = (t >= o) ? ps[t - o] : 0;
            __syncthreads();
            ps[t] += u;
            __syncthreads();
        }
        ubase[t] = ps[t] - s;
        pbase[t] = ps[t] - s + (uint32)t * 768u;
    }
}

// ---------------------------------------------------------------------------
// 3) Scatter edges into bin regions: rank within (block,bin) via LDS atomic,
//    position = ubase[bin] + blkoff[bin][block] + rank. Payload packs
//    src (16b) | dlocal (8b) in word0, ew fp32 bits in word1.
// ---------------------------------------------------------------------------
__global__ __launch_bounds__(256) void k_scatter(
    const int* __restrict__ src, const int* __restrict__ dst,
    const float* __restrict__ ew, const uint32* __restrict__ blkoff,
    const uint32* __restrict__ ubase, uint2* __restrict__ ebin)
{
    __shared__ uint32 bh[256];
    __shared__ uint32 bo[256];
    int b = blockIdx.x, t = threadIdx.x;
    bh[t] = 0;
    bo[t] = ubase[t] + blkoff[t * 512 + b];
    __syncthreads();
    int e0 = b * 1024 + t * 4;
    int4 d4 = *(const int4*)(dst + e0);
    int4 s4 = *(const int4*)(src + e0);
    float4 w4 = *(const float4*)(ew + e0);
    int bin; uint32 r;
    bin = d4.x >> 8; r = atomicAdd(&bh[bin], 1u);
    ebin[bo[bin] + r] = make_uint2((uint32)s4.x | ((uint32)(d4.x & 255) << 16), __float_as_uint(w4.x));
    bin = d4.y >> 8; r = atomicAdd(&bh[bin], 1u);
    ebin[bo[bin] + r] = make_uint2((uint32)s4.y | ((uint32)(d4.y & 255) << 16), __float_as_uint(w4.y));
    bin = d4.z >> 8; r = atomicAdd(&bh[bin], 1u);
    ebin[bo[bin] + r] = make_uint2((uint32)s4.z | ((uint32)(d4.z & 255) << 16), __float_as_uint(w4.z));
    bin = d4.w >> 8; r = atomicAdd(&bh[bin], 1u);
    ebin[bo[bin] + r] = make_uint2((uint32)s4.w | ((uint32)(d4.w & 255) << 16), __float_as_uint(w4.w));
}

// ---------------------------------------------------------------------------
// 4) Per-bin CSR build: stage bin edges in LDS, packed LDS hist-with-return
//    gives (rank, cnt, fixed-point wsum). Local padded scan -> absolute
//    rowp; write epk = (src, ew*dinv[d]) + pads. dinv[src] folded into GEMM1.
// ---------------------------------------------------------------------------
__global__ __launch_bounds__(256) void k_csr(
    const uint2* __restrict__ ebin, const uint32* __restrict__ binsz,
    const uint32* __restrict__ ubase, const uint32* __restrict__ pbase,
    float* __restrict__ dinv, int* __restrict__ rowp, int* __restrict__ cnts,
    int2* __restrict__ epk)
{
    __shared__ uint2 es[3072];        // bin edges (max 22 sigma above mean 2048)
    __shared__ uint32 hist[256];      // (cnt<<24) | wsum fixed-point 2^-18
    __shared__ int sscan[256];
    __shared__ int rloc[256];
    __shared__ float dlv[256];
    int g = blockIdx.x, t = threadIdx.x;
    int start = (int)ubase[g];
    int sz = min((int)binsz[g], 3072);
    int pb = (int)pbase[g];
    hist[t] = 0;
    __syncthreads();
    for (int i = t; i < sz; i += 256) {           // load + rank in one pass
        uint2 e = ebin[start + i];
        int dl = (e.x >> 16) & 255;
        uint32 wfix = __float2uint_rn(__uint_as_float(e.y) * 262144.0f);
        uint32 h = atomicAdd(&hist[dl], (1u << 24) | wfix);
        e.x |= (h >> 24) << 24;                   // rank (u8) into top byte
        es[i] = e;
    }
    __syncthreads();
    uint32 hv = hist[t];
    int cnt = (int)(hv >> 24);
    float di = rsqrtf((float)(hv & 0xFFFFFFu) * 3.814697265625e-6f + 1.0f);
    dlv[t] = di;
    dinv[g * 256 + t] = di;
    cnts[g * 256 + t] = cnt;
    int pcnt = (cnt + 3) & ~3;
    sscan[t] = pcnt; __syncthreads();
    for (int o = 1; o < 256; o <<= 1) {
        int u = (t >= o) ? sscan[t - o] : 0;
        __syncthreads();
        sscan[t] += u;
        __syncthreads();
    }
    int rl = sscan[t] - pcnt;
    rloc[t] = rl;
    rowp[g * 256 + t] = pb + rl;
    __syncthreads();
    for (int i = t; i < sz; i += 256) {
        uint2 e = es[i];
        int s  = (int)(e.x & 0xFFFFu);
        int dl = (int)((e.x >> 16) & 255u);
        int r  = (int)(e.x >> 24);
        float w = __uint_as_float(e.y) * dlv[dl];
        epk[pb + rloc[dl] + r] = make_int2(s, __float_as_int(w));
    }
    int base = pb + rl;
    for (int q = cnt; q < pcnt; q++) epk[base + q] = make_int2(g * 256 + t, 0);
}

// ---------------------------------------------------------------------------
// 5) xw = dinv ⊙ (BN1(h0) @ W1^T) via MFMA bf16.
// ---------------------------------------------------------------------------
__global__ __launch_bounds__(256) void k_gemm1f(
    const uint32* __restrict__ h0u, const uint32* __restrict__ w1bk,
    const float* __restrict__ g1, const float* __restrict__ bb1,
    const float* __restrict__ stats, ushort16* __restrict__ xws,
    const float* __restrict__ dinv)
{
    __shared__ short hn_s[64 * 136];    // bf16 bits, row-major, stride 136 (2-way max)
    __shared__ short w_s[128 * 136];
    __shared__ float sc[128], sf[128];
    int t = threadIdx.x;
    int blk = blockIdx.x;
    int row0 = blk * 64;

    if (t < 128) {
        float mu  = stats[t] * (1.0f / N_NODES);
        float var = stats[128 + t] * (1.0f / N_NODES) - mu * mu;
        float rs  = rsqrtf(fmaxf(var, 0.f) + BN_EPS);
        float s   = rs * g1[t];
        sc[t] = s;
        sf[t] = bb1[t] - mu * s;
    }
    __syncthreads();

    const uint4* h4 = (const uint4*)(h0u + (size_t)row0 * 64);
    #pragma unroll
    for (int it = 0; it < 4; it++) {
        int slot = it * 256 + t;
        int r = slot >> 4, k0 = (slot & 15) * 8;
        uint4 u = h4[slot];
        uint32 ua[4] = {u.x, u.y, u.z, u.w};
        uint32 o[4];
        #pragma unroll
        for (int m = 0; m < 4; m++) {
            int k = k0 + 2 * m;
            o[m] = packbf(blo(ua[m]) * sc[k] + sf[k], bhi(ua[m]) * sc[k + 1] + sf[k + 1]);
        }
        *(uint4*)&hn_s[r * 136 + k0] = make_uint4(o[0], o[1], o[2], o[3]);
    }
    const uint4* wv4 = (const uint4*)w1bk;
    #pragma unroll
    for (int it = 0; it < 8; it++) {
        int s2 = it * 256 + t;              // 2048 uint4 (8 bf16 each)
        int c = s2 >> 4, k0 = (s2 & 15) * 8;
        *(uint4*)&w_s[c * 136 + k0] = wv4[s2];
    }
    __syncthreads();

    int lane = t & 63, wave = t >> 6;
    int m16 = lane & 15, kh = lane >> 4;
    int mbase = wave * 16;
    f32x4 acc[8] = {};
    #pragma unroll
    for (int ks = 0; ks < 4; ks++) {
        short8 a = *(const short8*)&hn_s[(mbase + m16) * 136 + ks * 32 + kh * 8];
        #pragma unroll
        for (int ct = 0; ct < 8; ct++) {
            short8 bfr = *(const short8*)&w_s[(ct * 16 + m16) * 136 + ks * 32 + kh * 8];
            acc[ct] = __builtin_amdgcn_mfma_f32_16x16x32_bf16(a, bfr, acc[ct], 0, 0, 0);
        }
    }
    float dvr[4];
    #pragma unroll
    for (int r = 0; r < 4; r++) dvr[r] = dinv[row0 + mbase + kh * 4 + r];
    #pragma unroll
    for (int ct = 0; ct < 8; ct++) {
        int col = ct * 16 + m16;
        #pragma unroll
        for (int r = 0; r < 4; r++) {
            int row = mbase + kh * 4 + r;
            bf16 hv = __float2bfloat16(acc[ct][r] * dvr[r]);
            unsigned short us; __builtin_memcpy(&us, &hv, 2);
            xws[(size_t)(row0 + row) * 128 + col] = us;
        }
    }
}

// ---------------------------------------------------------------------------
// 6) CSR gather + fused BN2 stats. 2048 blocks x 256, 32 nodes/block, full
//    occupancy. 8-DEEP unroll: doubles in-flight random xwu loads per wave
//    (this phase is L3-latency-bound); 4-edge remainder.
// ---------------------------------------------------------------------------
__global__ __launch_bounds__(256) void k_gather(
    const int* __restrict__ rowp, const int* __restrict__ cnts,
    const int2* __restrict__ epk, const uint32* __restrict__ xwu,
    const float* __restrict__ dinv, const float2* __restrict__ b1c2,
    uint32* __restrict__ aggu, float* __restrict__ stats2r)
{
    __shared__ float sh[256];
    int t = threadIdx.x, b = blockIdx.x;
    int lane = t & 63, wave = t >> 6;
    float2 bb = b1c2[lane];
    float s0 = 0.f, ss0 = 0.f, s1 = 0.f, ss1 = 0.f;
    for (int it = 0; it < 8; it++) {
        int n = b * 32 + it * 4 + wave;
        int st = rowp[n];
        int pcnt = (cnts[n] + 3) & ~3;
        float di = dinv[n];
        uint32 u0 = xwu[(size_t)n * 64 + lane];
        float ax = di * blo(u0) + bb.x;
        float ay = di * bhi(u0) + bb.y;
        int en = st + pcnt;
        int p = st;
        for (; p + 8 <= en; p += 8) {
            int2 q0 = epk[p],     q1 = epk[p + 1], q2 = epk[p + 2], q3 = epk[p + 3];
            int2 q4 = epk[p + 4], q5 = epk[p + 5], q6 = epk[p + 6], q7 = epk[p + 7];
            uint32 v0 = xwu[(size_t)q0.x * 64 + lane];
            uint32 v1 = xwu[(size_t)q1.x * 64 + lane];
            uint32 v2 = xwu[(size_t)q2.x * 64 + lane];
            uint32 v3 = xwu[(size_t)q3.x * 64 + lane];
            uint32 v4 = xwu[(size_t)q4.x * 64 + lane];
            uint32 v5 = xwu[(size_t)q5.x * 64 + lane];
            uint32 v6 = xwu[(size_t)q6.x * 64 + lane];
            uint32 v7 = xwu[(size_t)q7.x * 64 + lane];
            float w0 = __int_as_float(q0.y), w1 = __int_as_float(q1.y);
            float w2 = __int_as_float(q2.y), w3 = __int_as_float(q3.y);
            float w4 = __int_as_float(q4.y), w5 = __int_as_float(q5.y);
            float w6 = __int_as_float(q6.y), w7 = __int_as_float(q7.y);
            ax += w0 * blo(v0) + w1 * blo(v1) + w2 * blo(v2) + w3 * blo(v3);
            ay += w0 * bhi(v0) + w1 * bhi(v1) + w2 * bhi(v2) + w3 * bhi(v3);
            ax += w4 * blo(v4) + w5 * blo(v5) + w6 * blo(v6) + w7 * blo(v7);
            ay += w4 * bhi(v4) + w5 * bhi(v5) + w6 * bhi(v6) + w7 * bhi(v7);
        }
        if (p < en) {
            int2 q0 = epk[p], q1 = epk[p + 1], q2 = epk[p + 2], q3 = epk[p + 3];
            uint32 v0 = xwu[(size_t)q0.x * 64 + lane];
            uint32 v1 = xwu[(size_t)q1.x * 64 + lane];
            uint32 v2 = xwu[(size_t)q2.x * 64 + lane];
            uint32 v3 = xwu[(size_t)q3.x * 64 + lane];
            float w0 = __int_as_float(q0.y), w1 = __int_as_float(q1.y);
            float w2 = __int_as_float(q2.y), w3 = __int_as_float(q3.y);
            ax += w0 * blo(v0) + w1 * blo(v1) + w2 * blo(v2) + w3 * blo(v3);
            ay += w0 * bhi(v0) + w1 * bhi(v1) + w2 * bhi(v2) + w3 * bhi(v3);
        }
        uint32 pk = packbf(ax, ay);
        aggu[(size_t)n * 64 + lane] = pk;
        float v0 = blo(pk), v1 = bhi(pk);
        s0 += v0; ss0 += v0 * v0; s1 += v1; ss1 += v1 * v1;
    }
    float* st2 = stats2r + (b & 7) * 256;
    sh[t] = s0; __syncthreads();
    if (t < 64) atomicAdd(&st2[2 * t], sh[t] + sh[t + 64] + sh[t + 128] + sh[t + 192]);
    __syncthreads(); sh[t] = s1; __syncthreads();
    if (t < 64) atomicAdd(&st2[2 * t + 1], sh[t] + sh[t + 64] + sh[t + 128] + sh[t + 192]);
    __syncthreads(); sh[t] = ss0; __syncthreads();
    if (t < 64) atomicAdd(&st2[128 + 2 * t], sh[t] + sh[t + 64] + sh[t + 128] + sh[t + 192]);
    __syncthreads(); sh[t] = ss1; __syncthreads();
    if (t < 64) atomicAdd(&st2[128 + 2 * t + 1], sh[t] + sh[t + 64] + sh[t + 128] + sh[t + 192]);
}

// ---------------------------------------------------------------------------
// 7) Fused pool + gemm2: block g computes pooled row g (LDS only), then
//    z1 row g = pooled_g @ W2^T.
// ---------------------------------------------------------------------------
__global__ __launch_bounds__(512) void k_poolg2(
    const uint32* __restrict__ aggu, const float* __restrict__ stats2r,
    const float* __restrict__ g2, const float* __restrict__ bb2,
    const float* __restrict__ w2, float* __restrict__ z1)
{
    __shared__ float sc[128], sf[128], sh[512], prow[128];
    int t = threadIdx.x, g = blockIdx.x;
    if (t < 128) {
        float su = 0.f, sq = 0.f;
        #pragma unroll
        for (int r = 0; r < 8; r++) {
            su += stats2r[r * 256 + t];
            sq += stats2r[r * 256 + 128 + t];
        }
        float mu  = su * (1.0f / N_NODES);
        float var = sq * (1.0f / N_NODES) - mu * mu;
        float rs  = rsqrtf(fmaxf(var, 0.f) + BN_EPS);
        float s   = rs * g2[t];
        sc[t] = s;
        sf[t] = bb2[t] - mu * s;
    }
    __syncthreads();
    int c = t & 63, grp = t >> 6;                 // 8 groups x 32 rows
    float c0s = sc[2 * c], c0f = sf[2 * c], c1s = sc[2 * c + 1], c1f = sf[2 * c + 1];
    const uint32* base = aggu + (size_t)g * 256 * 64;
    float s0 = 0.f, s1 = 0.f;
    for (int r = grp * 32; r < grp * 32 + 32; r++) {
        uint32 u = base[r * 64 + c];
        s0 += ftanh(blo(u) * c0s + c0f);
        s1 += ftanh(bhi(u) * c1s + c1f);
    }
    sh[t] = s0; __syncthreads();
    if (t < 64) {
        float acc = 0.f;
        #pragma unroll
        for (int k = 0; k < 8; k++) acc += sh[t + 64 * k];
        prow[2 * t] = acc * (1.0f / 256.0f);
    }
    __syncthreads(); sh[t] = s1; __syncthreads();
    if (t < 64) {
        float acc = 0.f;
        #pragma unroll
        for (int k = 0; k < 8; k++) acc += sh[t + 64 * k];
        prow[2 * t + 1] = acc * (1.0f / 256.0f);
    }
    __syncthreads();
    // ---- gemm2: z1[g][t] = sum_k prow[k] * w2[t][k], t < 256 ----
    if (t < 256) {
        float acc = 0.f;
        const float* wr = w2 + t * 128;
        for (int k = 0; k < 128; k++) acc += prow[k] * wr[k];
        z1[g * 256 + t] = acc;
    }
}

// y1 + fused BN3 stats into 8-way replicated accumulators
__global__ void k_dgcn1(const float* __restrict__ scen, const float* __restrict__ fcol,
                        const float* __restrict__ z1, const float* __restrict__ b2c,
                        float* __restrict__ y1, float* __restrict__ stats3r)
{
    __shared__ float wk[256];
    int i = blockIdx.x, t = threadIdx.x;
    float a = (scen[t * 256 + i] >= THRE) ? 1.0f : 0.0f;
    if (t == i) a += 1.0f;
    wk[t] = a * rsqrtf(fcol[t] + 1.0f);
    __syncthreads();
    float acc = 0.f;
    for (int k = 0; k < 256; k++) acc += wk[k] * z1[k * 256 + t];
    float v = rsqrtf(fcol[i] + 1.0f) * acc + b2c[t];
    y1[i * 256 + t] = v;
    float* s3 = stats3r + (i & 7) * 512;
    atomicAdd(&s3[t], v);
    atomicAdd(&s3[256 + t], v * v);
}

// z2 = tanh(BN3(y1)) @ W3^T : BN3+tanh applied while staging the row
__global__ void k_gemm3(const float* __restrict__ y1, const float* __restrict__ stats3r,
                        const float* __restrict__ g3, const float* __restrict__ bb3,
                        const float* __restrict__ w3, float* __restrict__ z2)
{
    __shared__ float row[256];
    int i = blockIdx.x, t = threadIdx.x;   // 256 blocks x 128
    for (int c = t; c < 256; c += 128) {
        float s = 0.f, ss = 0.f;
        #pragma unroll
        for (int r = 0; r < 8; r++) {
            s  += stats3r[r * 512 + c];
            ss += stats3r[r * 512 + 256 + c];
        }
        float mu  = s * (1.0f / 256.0f);
        float var = ss * (1.0f / 256.0f) - mu * mu;
        float rs  = rsqrtf(fmaxf(var, 0.f) + BN_EPS);
        float scj = rs * g3[c];
        float sfj = bb3[c] - mu * scj;
        row[c] = ftanh(y1[i * 256 + c] * scj + sfj);
    }
    __syncthreads();
    float acc = 0.f;
    const float* wr = w3 + t * 256;
    for (int k = 0; k < 256; k++) acc += row[k] * wr[k];
    z2[i * 128 + t] = acc;
}

// feat = tanh(dense GCN(z2)) -> out rows; mean via 8-way replicas; last
// finishing block folds replicas into the out tail.
__global__ void k_dgcn2(const float* __restrict__ scen, const float* __restrict__ fcol,
                        const float* __restrict__ z2, const float* __restrict__ b3c,
                        float* __restrict__ out, float* __restrict__ meanr,
                        int* __restrict__ ctr)
{
    __shared__ float wk[256];
    __shared__ int flag;
    int i = blockIdx.x, t = threadIdx.x;   // 256 blocks x 128
    for (int k = t; k < 256; k += 128) {
        float a = (scen[k * 256 + i] >= THRE) ? 1.0f : 0.0f;
        if (k == i) a += 1.0f;
        wk[k] = a * rsqrtf(fcol[k] + 1.0f);
    }
    __syncthreads();
    float acc = 0.f;
    for (int k = 0; k < 256; k++) acc += wk[k] * z2[k * 128 + t];
    float v = ftanh(rsqrtf(fcol[i] + 1.0f) * acc + b3c[t]);
    out[i * 128 + t] = v;
    atomicAdd(&meanr[(i & 7) * 128 + t], v);
    __syncthreads();
    if (t == 0) {
        __threadfence();
        flag = (atomicAdd(ctr, 1) == 255) ? 1 : 0;
    }
    __syncthreads();
    if (flag) {
        __threadfence();
        float s = 0.f;
        #pragma unroll
        for (int r = 0; r < 8; r++) s += meanr[r * 128 + t];
        out[S_GRAPH * 128 + t] = s * (1.0f / 256.0f);
    }
}

// ---------------------------------------------------------------------------
extern "C" void kernel_launch(void* const* d_in, const int* in_sizes, int n_in,
                              void* d_out, int out_size, void* d_ws, size_t ws_size,
                              hipStream_t stream)
{
    const float* x        = (const float*)d_in[0];
    const float* edge_attr= (const float*)d_in[1];
    const float* scen     = (const float*)d_in[2];
    const float* wv       = (const float*)d_in[3];
    const float* bv       = (const float*)d_in[4];
    const float* wc       = (const float*)d_in[5];
    const float* bc       = (const float*)d_in[6];
    const float* w1       = (const float*)d_in[7];
    const float* b1c      = (const float*)d_in[8];
    const float* w2       = (const float*)d_in[9];
    const float* b2c      = (const float*)d_in[10];
    const float* w3       = (const float*)d_in[11];
    const float* b3c      = (const float*)d_in[12];
    const float* g1       = (const float*)d_in[13];
    const float* bb1      = (const float*)d_in[14];
    const float* g2       = (const float*)d_in[15];
    const float* bb2      = (const float*)d_in[16];
    const float* g3       = (const float*)d_in[17];
    const float* bb3      = (const float*)d_in[18];
    const int*  ei        = (const int*)d_in[20];
    const int*  nconp     = (const int*)d_in[22];
    const int*  src = ei;
    const int*  dst = ei + N_EDGES;

    float* wsf = (float*)d_ws;
    uint32*   h0u  = (uint32*)wsf;            // 16.7MB, dead after gemm1
    uint32*   aggu = (uint32*)wsf;            // alias
    uint32*   xwu  = (uint32*)(wsf + 4194304);// 16.7MB
    float* zb      = wsf + 8388608;
    float* stats1  = zb;                      // 256 (non-atomic, from pstat)
    float* zacc    = zb + 512;                // stats2r(2048)+stats3r(4096)+meanr(1024)
    float* stats2r = zacc;                    // 2048
    float* stats3r = zacc + 2048;             // 4096
    float* meanr   = zacc + 6144;             // 1024
    float* fcol    = zb + 7680;               // 256 (non-atomic)
    int*   ctrs    = (int*)(zb + 7936);       // 8 counters (zeroed in k_mlp_hist)
    float* deg     = zb + 7944;               // 65536 (dinv)
    int*   rowp    = (int*)(deg + 65536);     // 65536 (absolute padded offsets)
    int*   cnts    = rowp + 65536;            // 65536
    uint32* blkhist= (uint32*)(cnts + 65536); // 512*256 [block][bin]
    uint32* blkoff = blkhist + 131072;        // 256*512 [bin][block]
    uint32* binsz  = blkoff + 131072;         // 256
    uint32* ubase  = binsz + 256;             // 256
    uint32* pbase  = ubase + 256;             // 256
    uint2* ebin    = (uint2*)(pbase + 256);   // 524288 uint2 (binned edges)
    int2*  epk     = (int2*)(ebin + 524288);  // 720896 int2 (padded CSR)
    uint32* w1bk   = (uint32*)(epk + 720896); // 8192 (32KB bf16 W1)
    float* z1      = (float*)(w1bk + 8192);   // 65536
    float* y1      = z1 + 65536;              // 65536
    float* z2      = y1 + 65536;              // 32768
    float* pstat   = z2 + 32768;              // 512*256 stats1 partials

    float* out = (float*)d_out;

    k_mlp_hist<<<1057, 256, 0, stream>>>(x, wv, bv, wc, bc, nconp, h0u, pstat,
                                         dst, blkhist, scen, fcol, w1, w1bk,
                                         zacc, ctrs);
    k_binscan<<<257, 256, 0, stream>>>(blkhist, blkoff, binsz, ubase, pbase,
                                       pstat, stats1, &ctrs[0]);
    k_scatter<<<512, 256, 0, stream>>>(src, dst, edge_attr, blkoff, ubase, ebin);
    k_csr<<<256, 256, 0, stream>>>(ebin, binsz, ubase, pbase, deg, rowp, cnts, epk);
    k_gemm1f<<<1024, 256, 0, stream>>>(h0u, w1bk, g1, bb1, stats1, (ushort16*)xwu, deg);
    k_gather<<<2048, 256, 0, stream>>>(rowp, cnts, epk, xwu, deg,
                                       (const float2*)b1c, aggu, stats2r);
    k_poolg2<<<S_GRAPH, 512, 0, stream>>>(aggu, stats2r, g2, bb2, w2, z1);
    k_dgcn1<<<256, 256, 0, stream>>>(scen, fcol, z1, b2c, y1, stats3r);
    k_gemm3<<<256, 128, 0, stream>>>(y1, stats3r, g3, bb3, w3, z2);
    k_dgcn2<<<256, 128, 0, stream>>>(scen, fcol, z2, b3c, out, meanr, &ctrs[1]);
}

// Round 11
// 237.879 us; speedup vs baseline: 2.3229x; 1.0039x over previous
//
#include <hip/hip_runtime.h>
#include <hip/hip_bf16.h>
#include <cstddef>

#define N_NODES 65536
#define N_EDGES 524288
#define S_GRAPH 256
#define BN_EPS 1e-5f
#define THRE 0.7f

typedef __hip_bfloat16 bf16;
typedef unsigned int uint32;
typedef unsigned char uchar;
typedef unsigned short ushort16;
typedef __attribute__((ext_vector_type(8))) short short8;
typedef __attribute__((ext_vector_type(4))) float f32x4;

__device__ __forceinline__ float blo(uint32 u) { return __uint_as_float(u << 16); }
__device__ __forceinline__ float bhi(uint32 u) { return __uint_as_float(u & 0xffff0000u); }

__device__ __forceinline__ uint32 packbf(float a, float b)
{
    bf16 ha = __float2bfloat16(a), hb = __float2bfloat16(b);
    unsigned short ua, ub;
    __builtin_memcpy(&ua, &ha, 2); __builtin_memcpy(&ub, &hb, 2);
    return (uint32)ua | ((uint32)ub << 16);
}

// fast tanh: 1 - 2/(e^{2x}+1); |err| ~1e-6, far below bf16 rounding (2^-9)
__device__ __forceinline__ float ftanh(float x)
{
    float e = __builtin_amdgcn_exp2f(x * 2.8853900817779268f);  // 2*log2(e)
    return 1.0f - 2.0f * __builtin_amdgcn_rcpf(e + 1.0f);
}

// ---------------------------------------------------------------------------
// 1) Fused front-end, 1057 blocks. No memset: accumulators are non-atomic
//    (stats1 partials, fcol) or zeroed here for later kernels.
//    [0..511]    coarse bin histogram (bin = dst>>8) -> blkhist
//    [512..1023] node MLP -> bf16 h0 + BN1 partial stats (non-atomic)
//    [1024]      fcol: dense adjacency column sums (single block)
//    [1056]      W1 fp32->bf16 pack + zero downstream accumulators
// ---------------------------------------------------------------------------
__global__ __launch_bounds__(256) void k_mlp_hist(
    const float* __restrict__ x, const float* __restrict__ wv,
    const float* __restrict__ bv, const float* __restrict__ wc,
    const float* __restrict__ bc, const int* __restrict__ nconp,
    uint32* __restrict__ h0u, float* __restrict__ pstat,
    const int* __restrict__ dst, uint32* __restrict__ blkhist,
    const float* __restrict__ scen, float* __restrict__ fcol,
    const float* __restrict__ w1f, uint32* __restrict__ w1bk,
    float* __restrict__ zacc, int* __restrict__ ctrs)
{
    __shared__ float xs[128 * 6];
    __shared__ float sh[256];
    __shared__ uint32 bh[256];
    int t = threadIdx.x;
    int b = blockIdx.x;
    if (b < 512) {                                // ---- bin histogram ----
        bh[t] = 0;
        __syncthreads();
        int e0 = b * 1024 + t * 4;
        int4 d4 = *(const int4*)(dst + e0);
        atomicAdd(&bh[d4.x >> 8], 1u);
        atomicAdd(&bh[d4.y >> 8], 1u);
        atomicAdd(&bh[d4.z >> 8], 1u);
        atomicAdd(&bh[d4.w >> 8], 1u);
        __syncthreads();
        blkhist[b * 256 + t] = bh[t];
        return;
    }
    if (b >= 1024) {
        if (b == 1024) {                          // ---- fcol, non-atomic ----
            float s = 0.f;
            for (int r = 0; r < 256; r++)
                s += (scen[r * 256 + t] >= THRE) ? 1.0f : 0.0f;
            fcol[t] = s;
        } else if (b == 1056) {                   // ---- W1 pack + zeroing ----
            const float4* w4 = (const float4*)w1f;
            uint2* wo = (uint2*)w1bk;
            #pragma unroll
            for (int it = 0; it < 16; it++) {
                int fi = it * 256 + t;            // 4096 float4
                float4 w = w4[fi];
                wo[fi] = make_uint2(packbf(w.x, w.y), packbf(w.z, w.w));
            }
            // zero stats2r(2048) + stats3r(4096) + meanr(1024) = 7168 floats
            for (int i = t; i < 7168; i += 256) zacc[i] = 0.f;
            if (t < 8) ctrs[t] = 0;
        }
        return;
    }
    // ---- node MLP path: block handles 128 nodes ----
    int n0 = (b - 512) * 128;
    if (t < 192) ((float4*)xs)[t] = ((const float4*)(x + (size_t)n0 * 6))[t];
    __syncthreads();

    int nc = *nconp;
    int lane = t & 63, wave = t >> 6;
    int j0 = 2 * lane;
    const float2* wv2 = (const float2*)wv;
    float2 wa0 = wv2[j0 * 3], wa1 = wv2[j0 * 3 + 1], wa2 = wv2[j0 * 3 + 2];
    float2 wb0 = wv2[j0 * 3 + 3], wb1 = wv2[j0 * 3 + 4], wb2 = wv2[j0 * 3 + 5];
    float wc0 = wc[j0], wc1 = wc[j0 + 1], bc0 = bc[j0], bc1 = bc[j0 + 1];
    float bv0 = bv[j0], bv1 = bv[j0 + 1];

    float s0 = 0.f, ss0 = 0.f, s1 = 0.f, ss1 = 0.f;
    #pragma unroll 4
    for (int m = 0; m < 32; m++) {
        int ln = wave * 32 + m;                   // local node, wave-uniform
        int n = n0 + ln;
        const float* xr = &xs[ln * 6];
        float a0, a1;
        if (n < nc) {
            float xv = xr[0];
            a0 = xv * wc0 + bc0; a1 = xv * wc1 + bc1;
        } else {
            float x0 = xr[0], x1 = xr[1], x2 = xr[2], x3 = xr[3], x4 = xr[4], x5 = xr[5];
            a0 = bv0 + x0 * wa0.x + x1 * wa0.y + x2 * wa1.x + x3 * wa1.y + x4 * wa2.x + x5 * wa2.y;
            a1 = bv1 + x0 * wb0.x + x1 * wb0.y + x2 * wb1.x + x3 * wb1.y + x4 * wb2.x + x5 * wb2.y;
        }
        uint32 pk = packbf(ftanh(a0), ftanh(a1));
        h0u[(size_t)n * 64 + lane] = pk;
        float v0 = blo(pk), v1 = bhi(pk);         // stats on rounded values
        s0 += v0; ss0 += v0 * v0; s1 += v1; ss1 += v1 * v1;
    }
    // per-block partial stats (non-atomic): layout [0..127]=sums, [128..255]=sqs
    float* pst = pstat + (size_t)(b - 512) * 256;
    sh[t] = s0; __syncthreads();
    if (t < 64) pst[2 * t] = sh[t] + sh[t + 64] + sh[t + 128] + sh[t + 192];
    __syncthreads(); sh[t] = s1; __syncthreads();
    if (t < 64) pst[2 * t + 1] = sh[t] + sh[t + 64] + sh[t + 128] + sh[t + 192];
    __syncthreads(); sh[t] = ss0; __syncthreads();
    if (t < 64) pst[128 + 2 * t] = sh[t] + sh[t + 64] + sh[t + 128] + sh[t + 192];
    __syncthreads(); sh[t] = ss1; __syncthreads();
    if (t < 64) pst[128 + 2 * t + 1] = sh[t] + sh[t + 64] + sh[t + 128] + sh[t + 192];
}

// ---------------------------------------------------------------------------
// 2) 257 blocks. [g<256]: per-bin scan of the 512 block-partials ->
//    blkoff[bin][block] + bin totals; last-finishing block scans bin totals
//    into ubase/pbase. [g==256]: reduce the 512 stats1 partials.
// ---------------------------------------------------------------------------
__global__ __launch_bounds__(256) void k_binscan(
    const uint32* __restrict__ blkhist, uint32* __restrict__ blkoff,
    uint32* __restrict__ binsz, uint32* __restrict__ ubase,
    uint32* __restrict__ pbase, const float* __restrict__ pstat,
    float* __restrict__ stats, int* __restrict__ ctr)
{
    __shared__ uint32 v[512];
    __shared__ uint32 ps[256];
    __shared__ int flag;
    int g = blockIdx.x, t = threadIdx.x;
    if (g == 256) {                               // ---- stats1 reduce ----
        float acc = 0.f;
        for (int j = 0; j < 512; j++) acc += pstat[j * 256 + t];
        stats[t] = acc;
        return;
    }
    v[t]       = blkhist[t * 256 + g];
    v[t + 256] = blkhist[(t + 256) * 256 + g];
    __syncthreads();
    uint32 a0 = v[2 * t], a1 = v[2 * t + 1];
    ps[t] = a0 + a1; __syncthreads();
    for (int o = 1; o < 256; o <<= 1) {
        uint32 u = (t >= o) ? ps[t - o] : 0;
        __syncthreads();
        ps[t] += u;
        __syncthreads();
    }
    uint32 ex = ps[t] - (a0 + a1);                // exclusive over block pairs
    ((uint2*)blkoff)[g * 256 + t] = make_uint2(ex, ex + a0);
    if (t == 255) atomicExch((int*)&binsz[g], (int)ps[255]);
    __syncthreads();
    if (t == 0) {
        __threadfence();
        flag = (atomicAdd(ctr, 1) == 255) ? 1 : 0;
    }
    __syncthreads();
    if (flag) {
        __threadfence();
        uint32 s = binsz[t];
        ps[t] = s; __syncthreads();
        for (int o = 1; o < 256; o <<= 1) {
            uint32 u = (t >= o) ? ps[t - o] : 0;
            __syncthreads();
            ps[t] += u;
            __syncthreads();
        }
        ubase[t] = ps[t] - s;
        pbase[t] = ps[t] - s + (uint32)t * 768u;
    }
}

// ---------------------------------------------------------------------------
// 3) FUSED scatter ∥ unscaled-GEMM1 (independent after binscan; disjoint
//    block ranges, NO grid barrier).
//    [0..511]    scatter edges into bin regions (verbatim body)
//    [512..1535] xwU = BN1(h0) @ W1^T (UNscaled; dinv applied later in k_csr)
// ---------------------------------------------------------------------------
__global__ __launch_bounds__(256) void k_sg(
    const int* __restrict__ src, const int* __restrict__ dst,
    const float* __restrict__ ew, const uint32* __restrict__ blkoff,
    const uint32* __restrict__ ubase, uint2* __restrict__ ebin,
    const uint32* __restrict__ h0u, const uint32* __restrict__ w1bk,
    const float* __restrict__ g1, const float* __restrict__ bb1,
    const float* __restrict__ stats, ushort16* __restrict__ xws)
{
    __shared__ __align__(16) uchar smem[53248];
    int t = threadIdx.x, b = blockIdx.x;
    if (b < 512) {                                // ---- scatter ----
        uint32* bh = (uint32*)smem;               // 256
        uint32* bo = (uint32*)(smem + 1024);      // 256
        bh[t] = 0;
        bo[t] = ubase[t] + blkoff[t * 512 + b];
        __syncthreads();
        int e0 = b * 1024 + t * 4;
        int4 d4 = *(const int4*)(dst + e0);
        int4 s4 = *(const int4*)(src + e0);
        float4 w4 = *(const float4*)(ew + e0);
        int bin; uint32 r;
        bin = d4.x >> 8; r = atomicAdd(&bh[bin], 1u);
        ebin[bo[bin] + r] = make_uint2((uint32)s4.x | ((uint32)(d4.x & 255) << 16), __float_as_uint(w4.x));
        bin = d4.y >> 8; r = atomicAdd(&bh[bin], 1u);
        ebin[bo[bin] + r] = make_uint2((uint32)s4.y | ((uint32)(d4.y & 255) << 16), __float_as_uint(w4.y));
        bin = d4.z >> 8; r = atomicAdd(&bh[bin], 1u);
        ebin[bo[bin] + r] = make_uint2((uint32)s4.z | ((uint32)(d4.z & 255) << 16), __float_as_uint(w4.z));
        bin = d4.w >> 8; r = atomicAdd(&bh[bin], 1u);
        ebin[bo[bin] + r] = make_uint2((uint32)s4.w | ((uint32)(d4.w & 255) << 16), __float_as_uint(w4.w));
        return;
    }
    // ---- unscaled GEMM1: block handles 64 rows ----
    short* hn_s = (short*)smem;                   // 64*136*2 = 17408B
    short* w_s  = (short*)(smem + 17408);         // 128*136*2 = 34816B
    float* sc   = (float*)(smem + 52224);         // 512B
    float* sf   = (float*)(smem + 52736);         // 512B
    int row0 = (b - 512) * 64;

    if (t < 128) {
        float mu  = stats[t] * (1.0f / N_NODES);
        float var = stats[128 + t] * (1.0f / N_NODES) - mu * mu;
        float rs  = rsqrtf(fmaxf(var, 0.f) + BN_EPS);
        float s   = rs * g1[t];
        sc[t] = s;
        sf[t] = bb1[t] - mu * s;
    }
    __syncthreads();

    const uint4* h4 = (const uint4*)(h0u + (size_t)row0 * 64);
    #pragma unroll
    for (int it = 0; it < 4; it++) {
        int slot = it * 256 + t;
        int r = slot >> 4, k0 = (slot & 15) * 8;
        uint4 u = h4[slot];
        uint32 ua[4] = {u.x, u.y, u.z, u.w};
        uint32 o[4];
        #pragma unroll
        for (int m = 0; m < 4; m++) {
            int k = k0 + 2 * m;
            o[m] = packbf(blo(ua[m]) * sc[k] + sf[k], bhi(ua[m]) * sc[k + 1] + sf[k + 1]);
        }
        *(uint4*)&hn_s[r * 136 + k0] = make_uint4(o[0], o[1], o[2], o[3]);
    }
    const uint4* wv4 = (const uint4*)w1bk;
    #pragma unroll
    for (int it = 0; it < 8; it++) {
        int s2 = it * 256 + t;              // 2048 uint4 (8 bf16 each)
        int c = s2 >> 4, k0 = (s2 & 15) * 8;
        *(uint4*)&w_s[c * 136 + k0] = wv4[s2];
    }
    __syncthreads();

    int lane = t & 63, wave = t >> 6;
    int m16 = lane & 15, kh = lane >> 4;
    int mbase = wave * 16;
    f32x4 acc[8] = {};
    #pragma unroll
    for (int ks = 0; ks < 4; ks++) {
        short8 a = *(const short8*)&hn_s[(mbase + m16) * 136 + ks * 32 + kh * 8];
        #pragma unroll
        for (int ct = 0; ct < 8; ct++) {
            short8 bfr = *(const short8*)&w_s[(ct * 16 + m16) * 136 + ks * 32 + kh * 8];
            acc[ct] = __builtin_amdgcn_mfma_f32_16x16x32_bf16(a, bfr, acc[ct], 0, 0, 0);
        }
    }
    #pragma unroll
    for (int ct = 0; ct < 8; ct++) {
        int col = ct * 16 + m16;
        #pragma unroll
        for (int r = 0; r < 4; r++) {
            int row = mbase + kh * 4 + r;
            bf16 hv = __float2bfloat16(acc[ct][r]);   // UNscaled
            unsigned short us; __builtin_memcpy(&us, &hv, 2);
            xws[(size_t)(row0 + row) * 128 + col] = us;
        }
    }
}

// ---------------------------------------------------------------------------
// 4) Per-bin CSR build + xwu dinv-scaling. Stage bin edges in LDS, packed
//    LDS hist-with-return gives (rank, cnt, fixed-point wsum). Local padded
//    scan -> absolute rowp; write epk = (src, ew*dinv[d]) + pads. Then scale
//    this bin's 256 xwu rows by dinv (the factor removed from the GEMM).
// ---------------------------------------------------------------------------
__global__ __launch_bounds__(256) void k_csr(
    const uint2* __restrict__ ebin, const uint32* __restrict__ binsz,
    const uint32* __restrict__ ubase, const uint32* __restrict__ pbase,
    float* __restrict__ dinv, int* __restrict__ rowp, int* __restrict__ cnts,
    int2* __restrict__ epk, uint32* __restrict__ xwu)
{
    __shared__ uint2 es[3072];        // bin edges (max 22 sigma above mean 2048)
    __shared__ uint32 hist[256];      // (cnt<<24) | wsum fixed-point 2^-18
    __shared__ int sscan[256];
    __shared__ int rloc[256];
    __shared__ float dlv[256];
    int g = blockIdx.x, t = threadIdx.x;
    int start = (int)ubase[g];
    int sz = min((int)binsz[g], 3072);
    int pb = (int)pbase[g];
    hist[t] = 0;
    __syncthreads();
    for (int i = t; i < sz; i += 256) {           // load + rank in one pass
        uint2 e = ebin[start + i];
        int dl = (e.x >> 16) & 255;
        uint32 wfix = __float2uint_rn(__uint_as_float(e.y) * 262144.0f);
        uint32 h = atomicAdd(&hist[dl], (1u << 24) | wfix);
        e.x |= (h >> 24) << 24;                   // rank (u8) into top byte
        es[i] = e;
    }
    __syncthreads();
    uint32 hv = hist[t];
    int cnt = (int)(hv >> 24);
    float di = rsqrtf((float)(hv & 0xFFFFFFu) * 3.814697265625e-6f + 1.0f);
    dlv[t] = di;
    dinv[g * 256 + t] = di;
    cnts[g * 256 + t] = cnt;
    int pcnt = (cnt + 3) & ~3;
    sscan[t] = pcnt; __syncthreads();
    for (int o = 1; o < 256; o <<= 1) {
        int u = (t >= o) ? sscan[t - o] : 0;
        __syncthreads();
        sscan[t] += u;
        __syncthreads();
    }
    int rl = sscan[t] - pcnt;
    rloc[t] = rl;
    rowp[g * 256 + t] = pb + rl;
    __syncthreads();
    for (int i = t; i < sz; i += 256) {
        uint2 e = es[i];
        int s  = (int)(e.x & 0xFFFFu);
        int dl = (int)((e.x >> 16) & 255u);
        int r  = (int)(e.x >> 24);
        float w = __uint_as_float(e.y) * dlv[dl];
        epk[pb + rloc[dl] + r] = make_int2(s, __float_as_int(w));
    }
    int base = pb + rl;
    for (int q = cnt; q < pcnt; q++) epk[base + q] = make_int2(g * 256 + t, 0);
    // ---- scale this bin's xwu rows by dinv (dlv valid since last sync) ----
    uint4* xr = (uint4*)(xwu + (size_t)g * 256 * 64);
    for (int i = t; i < 4096; i += 256) {         // 256 rows x 16 uint4
        float d = dlv[i >> 4];
        uint4 u = xr[i];
        u.x = packbf(blo(u.x) * d, bhi(u.x) * d);
        u.y = packbf(blo(u.y) * d, bhi(u.y) * d);
        u.z = packbf(blo(u.z) * d, bhi(u.z) * d);
        u.w = packbf(blo(u.w) * d, bhi(u.w) * d);
        xr[i] = u;
    }
}

// ---------------------------------------------------------------------------
// 5) CSR gather + fused BN2 stats. 2048 blocks x 256, 32 nodes/block, full
//    occupancy, 8-deep unroll (latency-bound phase).
// ---------------------------------------------------------------------------
__global__ __launch_bounds__(256) void k_gather(
    const int* __restrict__ rowp, const int* __restrict__ cnts,
    const int2* __restrict__ epk, const uint32* __restrict__ xwu,
    const float* __restrict__ dinv, const float2* __restrict__ b1c2,
    uint32* __restrict__ aggu, float* __restrict__ stats2r)
{
    __shared__ float sh[256];
    int t = threadIdx.x, b = blockIdx.x;
    int lane = t & 63, wave = t >> 6;
    float2 bb = b1c2[lane];
    float s0 = 0.f, ss0 = 0.f, s1 = 0.f, ss1 = 0.f;
    for (int it = 0; it < 8; it++) {
        int n = b * 32 + it * 4 + wave;
        int st = rowp[n];
        int pcnt = (cnts[n] + 3) & ~3;
        float di = dinv[n];
        uint32 u0 = xwu[(size_t)n * 64 + lane];
        float ax = di * blo(u0) + bb.x;
        float ay = di * bhi(u0) + bb.y;
        int en = st + pcnt;
        int p = st;
        for (; p + 8 <= en; p += 8) {
            int2 q0 = epk[p],     q1 = epk[p + 1], q2 = epk[p + 2], q3 = epk[p + 3];
            int2 q4 = epk[p + 4], q5 = epk[p + 5], q6 = epk[p + 6], q7 = epk[p + 7];
            uint32 v0 = xwu[(size_t)q0.x * 64 + lane];
            uint32 v1 = xwu[(size_t)q1.x * 64 + lane];
            uint32 v2 = xwu[(size_t)q2.x * 64 + lane];
            uint32 v3 = xwu[(size_t)q3.x * 64 + lane];
            uint32 v4 = xwu[(size_t)q4.x * 64 + lane];
            uint32 v5 = xwu[(size_t)q5.x * 64 + lane];
            uint32 v6 = xwu[(size_t)q6.x * 64 + lane];
            uint32 v7 = xwu[(size_t)q7.x * 64 + lane];
            float w0 = __int_as_float(q0.y), w1 = __int_as_float(q1.y);
            float w2 = __int_as_float(q2.y), w3 = __int_as_float(q3.y);
            float w4 = __int_as_float(q4.y), w5 = __int_as_float(q5.y);
            float w6 = __int_as_float(q6.y), w7 = __int_as_float(q7.y);
            ax += w0 * blo(v0) + w1 * blo(v1) + w2 * blo(v2) + w3 * blo(v3);
            ay += w0 * bhi(v0) + w1 * bhi(v1) + w2 * bhi(v2) + w3 * bhi(v3);
            ax += w4 * blo(v4) + w5 * blo(v5) + w6 * blo(v6) + w7 * blo(v7);
            ay += w4 * bhi(v4) + w5 * bhi(v5) + w6 * bhi(v6) + w7 * bhi(v7);
        }
        if (p < en) {
            int2 q0 = epk[p], q1 = epk[p + 1], q2 = epk[p + 2], q3 = epk[p + 3];
            uint32 v0 = xwu[(size_t)q0.x * 64 + lane];
            uint32 v1 = xwu[(size_t)q1.x * 64 + lane];
            uint32 v2 = xwu[(size_t)q2.x * 64 + lane];
            uint32 v3 = xwu[(size_t)q3.x * 64 + lane];
            float w0 = __int_as_float(q0.y), w1 = __int_as_float(q1.y);
            float w2 = __int_as_float(q2.y), w3 = __int_as_float(q3.y);
            ax += w0 * blo(v0) + w1 * blo(v1) + w2 * blo(v2) + w3 * blo(v3);
            ay += w0 * bhi(v0) + w1 * bhi(v1) + w2 * bhi(v2) + w3 * bhi(v3);
        }
        uint32 pk = packbf(ax, ay);
        aggu[(size_t)n * 64 + lane] = pk;
        float v0 = blo(pk), v1 = bhi(pk);
        s0 += v0; ss0 += v0 * v0; s1 += v1; ss1 += v1 * v1;
    }
    float* st2 = stats2r + (b & 7) * 256;
    sh[t] = s0; __syncthreads();
    if (t < 64) atomicAdd(&st2[2 * t], sh[t] + sh[t + 64] + sh[t + 128] + sh[t + 192]);
    __syncthreads(); sh[t] = s1; __syncthreads();
    if (t < 64) atomicAdd(&st2[2 * t + 1], sh[t] + sh[t + 64] + sh[t + 128] + sh[t + 192]);
    __syncthreads(); sh[t] = ss0; __syncthreads();
    if (t < 64) atomicAdd(&st2[128 + 2 * t], sh[t] + sh[t + 64] + sh[t + 128] + sh[t + 192]);
    __syncthreads(); sh[t] = ss1; __syncthreads();
    if (t < 64) atomicAdd(&st2[128 + 2 * t + 1], sh[t] + sh[t + 64] + sh[t + 128] + sh[t + 192]);
}

// ---------------------------------------------------------------------------
// 6) Fused pool + gemm2: block g computes pooled row g (LDS only), then
//    z1 row g = pooled_g @ W2^T.
// ---------------------------------------------------------------------------
__global__ __launch_bounds__(512) void k_poolg2(
    const uint32* __restrict__ aggu, const float* __restrict__ stats2r,
    const float* __restrict__ g2, const float* __restrict__ bb2,
    const float* __restrict__ w2, float* __restrict__ z1)
{
    __shared__ float sc[128], sf[128], sh[512], prow[128];
    int t = threadIdx.x, g = blockIdx.x;
    if (t < 128) {
        float su = 0.f, sq = 0.f;
        #pragma unroll
        for (int r = 0; r < 8; r++) {
            su += stats2r[r * 256 + t];
            sq += stats2r[r * 256 + 128 + t];
        }
        float mu  = su * (1.0f / N_NODES);
        float var = sq * (1.0f / N_NODES) - mu * mu;
        float rs  = rsqrtf(fmaxf(var, 0.f) + BN_EPS);
        float s   = rs * g2[t];
        sc[t] = s;
        sf[t] = bb2[t] - mu * s;
    }
    __syncthreads();
    int c = t & 63, grp = t >> 6;                 // 8 groups x 32 rows
    float c0s = sc[2 * c], c0f = sf[2 * c], c1s = sc[2 * c + 1], c1f = sf[2 * c + 1];
    const uint32* base = aggu + (size_t)g * 256 * 64;
    float s0 = 0.f, s1 = 0.f;
    for (int r = grp * 32; r < grp * 32 + 32; r++) {
        uint32 u = base[r * 64 + c];
        s0 += ftanh(blo(u) * c0s + c0f);
        s1 += ftanh(bhi(u) * c1s + c1f);
    }
    sh[t] = s0; __syncthreads();
    if (t < 64) {
        float acc = 0.f;
        #pragma unroll
        for (int k = 0; k < 8; k++) acc += sh[t + 64 * k];
        prow[2 * t] = acc * (1.0f / 256.0f);
    }
    __syncthreads(); sh[t] = s1; __syncthreads();
    if (t < 64) {
        float acc = 0.f;
        #pragma unroll
        for (int k = 0; k < 8; k++) acc += sh[t + 64 * k];
        prow[2 * t + 1] = acc * (1.0f / 256.0f);
    }
    __syncthreads();
    // ---- gemm2: z1[g][t] = sum_k prow[k] * w2[t][k], t < 256 ----
    if (t < 256) {
        float acc = 0.f;
        const float* wr = w2 + t * 128;
        for (int k = 0; k < 128; k++) acc += prow[k] * wr[k];
        z1[g * 256 + t] = acc;
    }
}

// y1 + fused BN3 stats into 8-way replicated accumulators
__global__ void k_dgcn1(const float* __restrict__ scen, const float* __restrict__ fcol,
                        const float* __restrict__ z1, const float* __restrict__ b2c,
                        float* __restrict__ y1, float* __restrict__ stats3r)
{
    __shared__ float wk[256];
    int i = blockIdx.x, t = threadIdx.x;
    float a = (scen[t * 256 + i] >= THRE) ? 1.0f : 0.0f;
    if (t == i) a += 1.0f;
    wk[t] = a * rsqrtf(fcol[t] + 1.0f);
    __syncthreads();
    float acc = 0.f;
    for (int k = 0; k < 256; k++) acc += wk[k] * z1[k * 256 + t];
    float v = rsqrtf(fcol[i] + 1.0f) * acc + b2c[t];
    y1[i * 256 + t] = v;
    float* s3 = stats3r + (i & 7) * 512;
    atomicAdd(&s3[t], v);
    atomicAdd(&s3[256 + t], v * v);
}

// z2 = tanh(BN3(y1)) @ W3^T : BN3+tanh applied while staging the row
__global__ void k_gemm3(const float* __restrict__ y1, const float* __restrict__ stats3r,
                        const float* __restrict__ g3, const float* __restrict__ bb3,
                        const float* __restrict__ w3, float* __restrict__ z2)
{
    __shared__ float row[256];
    int i = blockIdx.x, t = threadIdx.x;   // 256 blocks x 128
    for (int c = t; c < 256; c += 128) {
        float s = 0.f, ss = 0.f;
        #pragma unroll
        for (int r = 0; r < 8; r++) {
            s  += stats3r[r * 512 + c];
            ss += stats3r[r * 512 + 256 + c];
        }
        float mu  = s * (1.0f / 256.0f);
        float var = ss * (1.0f / 256.0f) - mu * mu;
        float rs  = rsqrtf(fmaxf(var, 0.f) + BN_EPS);
        float scj = rs * g3[c];
        float sfj = bb3[c] - mu * scj;
        row[c] = ftanh(y1[i * 256 + c] * scj + sfj);
    }
    __syncthreads();
    float acc = 0.f;
    const float* wr = w3 + t * 256;
    for (int k = 0; k < 256; k++) acc += row[k] * wr[k];
    z2[i * 128 + t] = acc;
}

// feat = tanh(dense GCN(z2)) -> out rows; mean via 8-way replicas; last
// finishing block folds replicas into the out tail.
__global__ void k_dgcn2(const float* __restrict__ scen, const float* __restrict__ fcol,
                        const float* __restrict__ z2, const float* __restrict__ b3c,
                        float* __restrict__ out, float* __restrict__ meanr,
                        int* __restrict__ ctr)
{
    __shared__ float wk[256];
    __shared__ int flag;
    int i = blockIdx.x, t = threadIdx.x;   // 256 blocks x 128
    for (int k = t; k < 256; k += 128) {
        float a = (scen[k * 256 + i] >= THRE) ? 1.0f : 0.0f;
        if (k == i) a += 1.0f;
        wk[k] = a * rsqrtf(fcol[k] + 1.0f);
    }
    __syncthreads();
    float acc = 0.f;
    for (int k = 0; k < 256; k++) acc += wk[k] * z2[k * 128 + t];
    float v = ftanh(rsqrtf(fcol[i] + 1.0f) * acc + b3c[t]);
    out[i * 128 + t] = v;
    atomicAdd(&meanr[(i & 7) * 128 + t], v);
    __syncthreads();
    if (t == 0) {
        __threadfence();
        flag = (atomicAdd(ctr, 1) == 255) ? 1 : 0;
    }
    __syncthreads();
    if (flag) {
        __threadfence();
        float s = 0.f;
        #pragma unroll
        for (int r = 0; r < 8; r++) s += meanr[r * 128 + t];
        out[S_GRAPH * 128 + t] = s * (1.0f / 256.0f);
    }
}

// ---------------------------------------------------------------------------
extern "C" void kernel_launch(void* const* d_in, const int* in_sizes, int n_in,
                              void* d_out, int out_size, void* d_ws, size_t ws_size,
                              hipStream_t stream)
{
    const float* x        = (const float*)d_in[0];
    const float* edge_attr= (const float*)d_in[1];
    const float* scen     = (const float*)d_in[2];
    const float* wv       = (const float*)d_in[3];
    const float* bv       = (const float*)d_in[4];
    const float* wc       = (const float*)d_in[5];
    const float* bc       = (const float*)d_in[6];
    const float* w1       = (const float*)d_in[7];
    const float* b1c      = (const float*)d_in[8];
    const float* w2       = (const float*)d_in[9];
    const float* b2c      = (const float*)d_in[10];
    const float* w3       = (const float*)d_in[11];
    const float* b3c      = (const float*)d_in[12];
    const float* g1       = (const float*)d_in[13];
    const float* bb1      = (const float*)d_in[14];
    const float* g2       = (const float*)d_in[15];
    const float* bb2      = (const float*)d_in[16];
    const float* g3       = (const float*)d_in[17];
    const float* bb3      = (const float*)d_in[18];
    const int*  ei        = (const int*)d_in[20];
    const int*  nconp     = (const int*)d_in[22];
    const int*  src = ei;
    const int*  dst = ei + N_EDGES;

    float* wsf = (float*)d_ws;
    uint32*   h0u  = (uint32*)wsf;            // 16.7MB, dead after gemm1
    uint32*   aggu = (uint32*)wsf;            // alias
    uint32*   xwu  = (uint32*)(wsf + 4194304);// 16.7MB
    float* zb      = wsf + 8388608;
    float* stats1  = zb;                      // 256 (non-atomic, from pstat)
    float* zacc    = zb + 512;                // stats2r(2048)+stats3r(4096)+meanr(1024)
    float* stats2r = zacc;                    // 2048
    float* stats3r = zacc + 2048;             // 4096
    float* meanr   = zacc + 6144;             // 1024
    float* fcol    = zb + 7680;               // 256 (non-atomic)
    int*   ctrs    = (int*)(zb + 7936);       // 8 counters (zeroed in k_mlp_hist)
    float* deg     = zb + 7944;               // 65536 (dinv)
    int*   rowp    = (int*)(deg + 65536);     // 65536 (absolute padded offsets)
    int*   cnts    = rowp + 65536;            // 65536
    uint32* blkhist= (uint32*)(cnts + 65536); // 512*256 [block][bin]
    uint32* blkoff = blkhist + 131072;        // 256*512 [bin][block]
    uint32* binsz  = blkoff + 131072;         // 256
    uint32* ubase  = binsz + 256;             // 256
    uint32* pbase  = ubase + 256;             // 256
    uint2* ebin    = (uint2*)(pbase + 256);   // 524288 uint2 (binned edges)
    int2*  epk     = (int2*)(ebin + 524288);  // 720896 int2 (padded CSR)
    uint32* w1bk   = (uint32*)(epk + 720896); // 8192 (32KB bf16 W1)
    float* z1      = (float*)(w1bk + 8192);   // 65536
    float* y1      = z1 + 65536;              // 65536
    float* z2      = y1 + 65536;              // 32768
    float* pstat   = z2 + 32768;              // 512*256 stats1 partials

    float* out = (float*)d_out;

    k_mlp_hist<<<1057, 256, 0, stream>>>(x, wv, bv, wc, bc, nconp, h0u, pstat,
                                         dst, blkhist, scen, fcol, w1, w1bk,
                                         zacc, ctrs);
    k_binscan<<<257, 256, 0, stream>>>(blkhist, blkoff, binsz, ubase, pbase,
                                       pstat, stats1, &ctrs[0]);
    k_sg<<<1536, 256, 0, stream>>>(src, dst, edge_attr, blkoff, ubase, ebin,
                                   h0u, w1bk, g1, bb1, stats1, (ushort16*)xwu);
    k_csr<<<256, 256, 0, stream>>>(ebin, binsz, ubase, pbase, deg, rowp, cnts,
                                   epk, xwu);
    k_gather<<<2048, 256, 0, stream>>>(rowp, cnts, epk, xwu, deg,
                                       (const float2*)b1c, aggu, stats2r);
    k_poolg2<<<S_GRAPH, 512, 0, stream>>>(aggu, stats2r, g2, bb2, w2, z1);
    k_dgcn1<<<256, 256, 0, stream>>>(scen, fcol, z1, b2c, y1, stats3r);
    k_gemm3<<<256, 128, 0, stream>>>(y1, stats3r, g3, bb3, w3, z2);
    k_dgcn2<<<256, 128, 0, stream>>>(scen, fcol, z2, b3c, out, meanr, &ctrs[1]);
}

// Round 12
// 236.509 us; speedup vs baseline: 2.3364x; 1.0058x over previous
//
#include <hip/hip_runtime.h>
#include <hip/hip_bf16.h>
#include <cstddef>

#define N_NODES 65536
#define N_EDGES 524288
#define S_GRAPH 256
#define BN_EPS 1e-5f
#define THRE 0.7f

typedef __hip_bfloat16 bf16;
typedef unsigned int uint32;
typedef unsigned char uchar;
typedef unsigned short ushort16;
typedef __attribute__((ext_vector_type(8))) short short8;
typedef __attribute__((ext_vector_type(4))) float f32x4;

__device__ __forceinline__ float blo(uint32 u) { return __uint_as_float(u << 16); }
__device__ __forceinline__ float bhi(uint32 u) { return __uint_as_float(u & 0xffff0000u); }

__device__ __forceinline__ uint32 packbf(float a, float b)
{
    bf16 ha = __float2bfloat16(a), hb = __float2bfloat16(b);
    unsigned short ua, ub;
    __builtin_memcpy(&ua, &ha, 2); __builtin_memcpy(&ub, &hb, 2);
    return (uint32)ua | ((uint32)ub << 16);
}

// fast tanh: 1 - 2/(e^{2x}+1); |err| ~1e-6, far below bf16 rounding (2^-9)
__device__ __forceinline__ float ftanh(float x)
{
    float e = __builtin_amdgcn_exp2f(x * 2.8853900817779268f);  // 2*log2(e)
    return 1.0f - 2.0f * __builtin_amdgcn_rcpf(e + 1.0f);
}

// ---------------------------------------------------------------------------
// 1) Fused front-end, 1057 blocks. No memset: accumulators are non-atomic
//    (stats1 partials, fcol) or zeroed here for later kernels.
//    [0..511]    coarse bin histogram (bin = dst>>8) -> blkhist
//    [512..1023] node MLP -> bf16 h0 + BN1 partial stats (non-atomic)
//    [1024]      fcol: dense adjacency column sums (single block)
//    [1056]      W1 fp32->bf16 pack + zero downstream accumulators
// ---------------------------------------------------------------------------
__global__ __launch_bounds__(256) void k_mlp_hist(
    const float* __restrict__ x, const float* __restrict__ wv,
    const float* __restrict__ bv, const float* __restrict__ wc,
    const float* __restrict__ bc, const int* __restrict__ nconp,
    uint32* __restrict__ h0u, float* __restrict__ pstat,
    const int* __restrict__ dst, uint32* __restrict__ blkhist,
    const float* __restrict__ scen, float* __restrict__ fcol,
    const float* __restrict__ w1f, uint32* __restrict__ w1bk,
    float* __restrict__ zacc, int* __restrict__ ctrs)
{
    __shared__ float xs[128 * 6];
    __shared__ float sh[256];
    __shared__ uint32 bh[256];
    int t = threadIdx.x;
    int b = blockIdx.x;
    if (b < 512) {                                // ---- bin histogram ----
        bh[t] = 0;
        __syncthreads();
        int e0 = b * 1024 + t * 4;
        int4 d4 = *(const int4*)(dst + e0);
        atomicAdd(&bh[d4.x >> 8], 1u);
        atomicAdd(&bh[d4.y >> 8], 1u);
        atomicAdd(&bh[d4.z >> 8], 1u);
        atomicAdd(&bh[d4.w >> 8], 1u);
        __syncthreads();
        blkhist[b * 256 + t] = bh[t];
        return;
    }
    if (b >= 1024) {
        if (b == 1024) {                          // ---- fcol, non-atomic ----
            float s = 0.f;
            for (int r = 0; r < 256; r++)
                s += (scen[r * 256 + t] >= THRE) ? 1.0f : 0.0f;
            fcol[t] = s;
        } else if (b == 1056) {                   // ---- W1 pack + zeroing ----
            const float4* w4 = (const float4*)w1f;
            uint2* wo = (uint2*)w1bk;
            #pragma unroll
            for (int it = 0; it < 16; it++) {
                int fi = it * 256 + t;            // 4096 float4
                float4 w = w4[fi];
                wo[fi] = make_uint2(packbf(w.x, w.y), packbf(w.z, w.w));
            }
            // zero stats2r(2048) + stats3r(4096) + meanr(1024) = 7168 floats
            for (int i = t; i < 7168; i += 256) zacc[i] = 0.f;
            if (t < 8) ctrs[t] = 0;
        }
        return;
    }
    // ---- node MLP path: block handles 128 nodes ----
    int n0 = (b - 512) * 128;
    if (t < 192) ((float4*)xs)[t] = ((const float4*)(x + (size_t)n0 * 6))[t];
    __syncthreads();

    int nc = *nconp;
    int lane = t & 63, wave = t >> 6;
    int j0 = 2 * lane;
    const float2* wv2 = (const float2*)wv;
    float2 wa0 = wv2[j0 * 3], wa1 = wv2[j0 * 3 + 1], wa2 = wv2[j0 * 3 + 2];
    float2 wb0 = wv2[j0 * 3 + 3], wb1 = wv2[j0 * 3 + 4], wb2 = wv2[j0 * 3 + 5];
    float wc0 = wc[j0], wc1 = wc[j0 + 1], bc0 = bc[j0], bc1 = bc[j0 + 1];
    float bv0 = bv[j0], bv1 = bv[j0 + 1];

    float s0 = 0.f, ss0 = 0.f, s1 = 0.f, ss1 = 0.f;
    #pragma unroll 4
    for (int m = 0; m < 32; m++) {
        int ln = wave * 32 + m;                   // local node, wave-uniform
        int n = n0 + ln;
        const float* xr = &xs[ln * 6];
        float a0, a1;
        if (n < nc) {
            float xv = xr[0];
            a0 = xv * wc0 + bc0; a1 = xv * wc1 + bc1;
        } else {
            float x0 = xr[0], x1 = xr[1], x2 = xr[2], x3 = xr[3], x4 = xr[4], x5 = xr[5];
            a0 = bv0 + x0 * wa0.x + x1 * wa0.y + x2 * wa1.x + x3 * wa1.y + x4 * wa2.x + x5 * wa2.y;
            a1 = bv1 + x0 * wb0.x + x1 * wb0.y + x2 * wb1.x + x3 * wb1.y + x4 * wb2.x + x5 * wb2.y;
        }
        uint32 pk = packbf(ftanh(a0), ftanh(a1));
        h0u[(size_t)n * 64 + lane] = pk;
        float v0 = blo(pk), v1 = bhi(pk);         // stats on rounded values
        s0 += v0; ss0 += v0 * v0; s1 += v1; ss1 += v1 * v1;
    }
    // per-block partial stats (non-atomic): layout [0..127]=sums, [128..255]=sqs
    float* pst = pstat + (size_t)(b - 512) * 256;
    sh[t] = s0; __syncthreads();
    if (t < 64) pst[2 * t] = sh[t] + sh[t + 64] + sh[t + 128] + sh[t + 192];
    __syncthreads(); sh[t] = s1; __syncthreads();
    if (t < 64) pst[2 * t + 1] = sh[t] + sh[t + 64] + sh[t + 128] + sh[t + 192];
    __syncthreads(); sh[t] = ss0; __syncthreads();
    if (t < 64) pst[128 + 2 * t] = sh[t] + sh[t + 64] + sh[t + 128] + sh[t + 192];
    __syncthreads(); sh[t] = ss1; __syncthreads();
    if (t < 64) pst[128 + 2 * t + 1] = sh[t] + sh[t + 64] + sh[t + 128] + sh[t + 192];
}

// ---------------------------------------------------------------------------
// 2) 257 blocks. [g<256]: per-bin scan of the 512 block-partials ->
//    blkoff[bin][block] + bin totals; last-finishing block scans bin totals
//    into ubase/pbase. [g==256]: reduce the 512 stats1 partials.
// ---------------------------------------------------------------------------
__global__ __launch_bounds__(256) void k_binscan(
    const uint32* __restrict__ blkhist, uint32* __restrict__ blkoff,
    uint32* __restrict__ binsz, uint32* __restrict__ ubase,
    uint32* __restrict__ pbase, const float* __restrict__ pstat,
    float* __restrict__ stats, int* __restrict__ ctr)
{
    __shared__ uint32 v[512];
    __shared__ uint32 ps[256];
    __shared__ int flag;
    int g = blockIdx.x, t = threadIdx.x;
    if (g == 256) {                               // ---- stats1 reduce ----
        float acc = 0.f;
        for (int j = 0; j < 512; j++) acc += pstat[j * 256 + t];
        stats[t] = acc;
        return;
    }
    v[t]       = blkhist[t * 256 + g];
    v[t + 256] = blkhist[(t + 256) * 256 + g];
    __syncthreads();
    uint32 a0 = v[2 * t], a1 = v[2 * t + 1];
    ps[t] = a0 + a1; __syncthreads();
    for (int o = 1; o < 256; o <<= 1) {
        uint32 u = (t >= o) ? ps[t - o] : 0;
        __syncthreads();
        ps[t] += u;
        __syncthreads();
    }
    uint32 ex = ps[t] - (a0 + a1);                // exclusive over block pairs
    ((uint2*)blkoff)[g * 256 + t] = make_uint2(ex, ex + a0);
    if (t == 255) atomicExch((int*)&binsz[g], (int)ps[255]);
    __syncthreads();
    if (t == 0) {
        __threadfence();
        flag = (atomicAdd(ctr, 1) == 255) ? 1 : 0;
    }
    __syncthreads();
    if (flag) {
        __threadfence();
        uint32 s = binsz[t];
        ps[t] = s; __syncthreads();
        for (int o = 1; o < 256; o <<= 1) {
            uint32 u = (t >= o) ? ps[t - o] : 0;
            __syncthreads();
            ps[t] += u;
            __syncthreads();
        }
        ubase[t] = ps[t] - s;
        pbase[t] = ps[t] - s + (uint32)t * 768u;
    }
}

// ---------------------------------------------------------------------------
// 3) FUSED scatter ∥ unscaled-GEMM1 (independent after binscan; disjoint
//    block ranges, NO grid barrier).
//    [0..511]    scatter edges into bin regions
//    [512..1535] xwU = BN1(h0) @ W1^T (UNscaled; dinv[s] applied in gather)
// ---------------------------------------------------------------------------
__global__ __launch_bounds__(256) void k_sg(
    const int* __restrict__ src, const int* __restrict__ dst,
    const float* __restrict__ ew, const uint32* __restrict__ blkoff,
    const uint32* __restrict__ ubase, uint2* __restrict__ ebin,
    const uint32* __restrict__ h0u, const uint32* __restrict__ w1bk,
    const float* __restrict__ g1, const float* __restrict__ bb1,
    const float* __restrict__ stats, ushort16* __restrict__ xws)
{
    __shared__ __align__(16) uchar smem[53248];
    int t = threadIdx.x, b = blockIdx.x;
    if (b < 512) {                                // ---- scatter ----
        uint32* bh = (uint32*)smem;               // 256
        uint32* bo = (uint32*)(smem + 1024);      // 256
        bh[t] = 0;
        bo[t] = ubase[t] + blkoff[t * 512 + b];
        __syncthreads();
        int e0 = b * 1024 + t * 4;
        int4 d4 = *(const int4*)(dst + e0);
        int4 s4 = *(const int4*)(src + e0);
        float4 w4 = *(const float4*)(ew + e0);
        int bin; uint32 r;
        bin = d4.x >> 8; r = atomicAdd(&bh[bin], 1u);
        ebin[bo[bin] + r] = make_uint2((uint32)s4.x | ((uint32)(d4.x & 255) << 16), __float_as_uint(w4.x));
        bin = d4.y >> 8; r = atomicAdd(&bh[bin], 1u);
        ebin[bo[bin] + r] = make_uint2((uint32)s4.y | ((uint32)(d4.y & 255) << 16), __float_as_uint(w4.y));
        bin = d4.z >> 8; r = atomicAdd(&bh[bin], 1u);
        ebin[bo[bin] + r] = make_uint2((uint32)s4.z | ((uint32)(d4.z & 255) << 16), __float_as_uint(w4.z));
        bin = d4.w >> 8; r = atomicAdd(&bh[bin], 1u);
        ebin[bo[bin] + r] = make_uint2((uint32)s4.w | ((uint32)(d4.w & 255) << 16), __float_as_uint(w4.w));
        return;
    }
    // ---- unscaled GEMM1: block handles 64 rows ----
    short* hn_s = (short*)smem;                   // 64*136*2 = 17408B
    short* w_s  = (short*)(smem + 17408);         // 128*136*2 = 34816B
    float* sc   = (float*)(smem + 52224);         // 512B
    float* sf   = (float*)(smem + 52736);         // 512B
    int row0 = (b - 512) * 64;

    if (t < 128) {
        float mu  = stats[t] * (1.0f / N_NODES);
        float var = stats[128 + t] * (1.0f / N_NODES) - mu * mu;
        float rs  = rsqrtf(fmaxf(var, 0.f) + BN_EPS);
        float s   = rs * g1[t];
        sc[t] = s;
        sf[t] = bb1[t] - mu * s;
    }
    __syncthreads();

    const uint4* h4 = (const uint4*)(h0u + (size_t)row0 * 64);
    #pragma unroll
    for (int it = 0; it < 4; it++) {
        int slot = it * 256 + t;
        int r = slot >> 4, k0 = (slot & 15) * 8;
        uint4 u = h4[slot];
        uint32 ua[4] = {u.x, u.y, u.z, u.w};
        uint32 o[4];
        #pragma unroll
        for (int m = 0; m < 4; m++) {
            int k = k0 + 2 * m;
            o[m] = packbf(blo(ua[m]) * sc[k] + sf[k], bhi(ua[m]) * sc[k + 1] + sf[k + 1]);
        }
        *(uint4*)&hn_s[r * 136 + k0] = make_uint4(o[0], o[1], o[2], o[3]);
    }
    const uint4* wv4 = (const uint4*)w1bk;
    #pragma unroll
    for (int it = 0; it < 8; it++) {
        int s2 = it * 256 + t;              // 2048 uint4 (8 bf16 each)
        int c = s2 >> 4, k0 = (s2 & 15) * 8;
        *(uint4*)&w_s[c * 136 + k0] = wv4[s2];
    }
    __syncthreads();

    int lane = t & 63, wave = t >> 6;
    int m16 = lane & 15, kh = lane >> 4;
    int mbase = wave * 16;
    f32x4 acc[8] = {};
    #pragma unroll
    for (int ks = 0; ks < 4; ks++) {
        short8 a = *(const short8*)&hn_s[(mbase + m16) * 136 + ks * 32 + kh * 8];
        #pragma unroll
        for (int ct = 0; ct < 8; ct++) {
            short8 bfr = *(const short8*)&w_s[(ct * 16 + m16) * 136 + ks * 32 + kh * 8];
            acc[ct] = __builtin_amdgcn_mfma_f32_16x16x32_bf16(a, bfr, acc[ct], 0, 0, 0);
        }
    }
    #pragma unroll
    for (int ct = 0; ct < 8; ct++) {
        int col = ct * 16 + m16;
        #pragma unroll
        for (int r = 0; r < 4; r++) {
            int row = mbase + kh * 4 + r;
            bf16 hv = __float2bfloat16(acc[ct][r]);   // UNscaled
            unsigned short us; __builtin_memcpy(&us, &hv, 2);
            xws[(size_t)(row0 + row) * 128 + col] = us;
        }
    }
}

// ---------------------------------------------------------------------------
// 4) Per-bin CSR build (no xwu scaling — dinv[s] applied in gather). Stage
//    bin edges in LDS, packed LDS hist-with-return gives (rank, cnt,
//    fixed-point wsum). Local padded scan -> absolute rowp; write
//    epk = (src, ew*dinv[d]) + pads.
// ---------------------------------------------------------------------------
__global__ __launch_bounds__(256) void k_csr(
    const uint2* __restrict__ ebin, const uint32* __restrict__ binsz,
    const uint32* __restrict__ ubase, const uint32* __restrict__ pbase,
    float* __restrict__ dinv, int* __restrict__ rowp, int* __restrict__ cnts,
    int2* __restrict__ epk)
{
    __shared__ uint2 es[3072];        // bin edges (max 22 sigma above mean 2048)
    __shared__ uint32 hist[256];      // (cnt<<24) | wsum fixed-point 2^-18
    __shared__ int sscan[256];
    __shared__ int rloc[256];
    __shared__ float dlv[256];
    int g = blockIdx.x, t = threadIdx.x;
    int start = (int)ubase[g];
    int sz = min((int)binsz[g], 3072);
    int pb = (int)pbase[g];
    hist[t] = 0;
    __syncthreads();
    for (int i = t; i < sz; i += 256) {           // load + rank in one pass
        uint2 e = ebin[start + i];
        int dl = (e.x >> 16) & 255;
        uint32 wfix = __float2uint_rn(__uint_as_float(e.y) * 262144.0f);
        uint32 h = atomicAdd(&hist[dl], (1u << 24) | wfix);
        e.x |= (h >> 24) << 24;                   // rank (u8) into top byte
        es[i] = e;
    }
    __syncthreads();
    uint32 hv = hist[t];
    int cnt = (int)(hv >> 24);
    float di = rsqrtf((float)(hv & 0xFFFFFFu) * 3.814697265625e-6f + 1.0f);
    dlv[t] = di;
    dinv[g * 256 + t] = di;
    cnts[g * 256 + t] = cnt;
    int pcnt = (cnt + 3) & ~3;
    sscan[t] = pcnt; __syncthreads();
    for (int o = 1; o < 256; o <<= 1) {
        int u = (t >= o) ? sscan[t - o] : 0;
        __syncthreads();
        sscan[t] += u;
        __syncthreads();
    }
    int rl = sscan[t] - pcnt;
    rloc[t] = rl;
    rowp[g * 256 + t] = pb + rl;
    __syncthreads();
    for (int i = t; i < sz; i += 256) {
        uint2 e = es[i];
        int s  = (int)(e.x & 0xFFFFu);
        int dl = (int)((e.x >> 16) & 255u);
        int r  = (int)(e.x >> 24);
        float w = __uint_as_float(e.y) * dlv[dl];
        epk[pb + rloc[dl] + r] = make_int2(s, __float_as_int(w));
    }
    int base = pb + rl;
    for (int q = cnt; q < pcnt; q++) epk[base + q] = make_int2(g * 256 + t, 0);
}

// ---------------------------------------------------------------------------
// 5) CSR gather + fused BN2 stats. 2048 blocks x 256, 32 nodes/block, full
//    occupancy, 8-deep unroll. dinv[s] looked up per edge (wave-uniform
//    broadcast, dinv L2-resident); self term = dinv[n]^2 (xwu unscaled).
// ---------------------------------------------------------------------------
__global__ __launch_bounds__(256) void k_gather(
    const int* __restrict__ rowp, const int* __restrict__ cnts,
    const int2* __restrict__ epk, const uint32* __restrict__ xwu,
    const float* __restrict__ dinv, const float2* __restrict__ b1c2,
    uint32* __restrict__ aggu, float* __restrict__ stats2r)
{
    __shared__ float sh[256];
    int t = threadIdx.x, b = blockIdx.x;
    int lane = t & 63, wave = t >> 6;
    float2 bb = b1c2[lane];
    float s0 = 0.f, ss0 = 0.f, s1 = 0.f, ss1 = 0.f;
    for (int it = 0; it < 8; it++) {
        int n = b * 32 + it * 4 + wave;
        int st = rowp[n];
        int pcnt = (cnts[n] + 3) & ~3;
        float di = dinv[n];
        float d2 = di * di;
        uint32 u0 = xwu[(size_t)n * 64 + lane];
        float ax = d2 * blo(u0) + bb.x;
        float ay = d2 * bhi(u0) + bb.y;
        int en = st + pcnt;
        int p = st;
        for (; p + 8 <= en; p += 8) {
            int2 q0 = epk[p],     q1 = epk[p + 1], q2 = epk[p + 2], q3 = epk[p + 3];
            int2 q4 = epk[p + 4], q5 = epk[p + 5], q6 = epk[p + 6], q7 = epk[p + 7];
            uint32 v0 = xwu[(size_t)q0.x * 64 + lane];
            uint32 v1 = xwu[(size_t)q1.x * 64 + lane];
            uint32 v2 = xwu[(size_t)q2.x * 64 + lane];
            uint32 v3 = xwu[(size_t)q3.x * 64 + lane];
            uint32 v4 = xwu[(size_t)q4.x * 64 + lane];
            uint32 v5 = xwu[(size_t)q5.x * 64 + lane];
            uint32 v6 = xwu[(size_t)q6.x * 64 + lane];
            uint32 v7 = xwu[(size_t)q7.x * 64 + lane];
            float w0 = __int_as_float(q0.y) * dinv[q0.x];
            float w1 = __int_as_float(q1.y) * dinv[q1.x];
            float w2 = __int_as_float(q2.y) * dinv[q2.x];
            float w3 = __int_as_float(q3.y) * dinv[q3.x];
            float w4 = __int_as_float(q4.y) * dinv[q4.x];
            float w5 = __int_as_float(q5.y) * dinv[q5.x];
            float w6 = __int_as_float(q6.y) * dinv[q6.x];
            float w7 = __int_as_float(q7.y) * dinv[q7.x];
            ax += w0 * blo(v0) + w1 * blo(v1) + w2 * blo(v2) + w3 * blo(v3);
            ay += w0 * bhi(v0) + w1 * bhi(v1) + w2 * bhi(v2) + w3 * bhi(v3);
            ax += w4 * blo(v4) + w5 * blo(v5) + w6 * blo(v6) + w7 * blo(v7);
            ay += w4 * bhi(v4) + w5 * bhi(v5) + w6 * bhi(v6) + w7 * bhi(v7);
        }
        if (p < en) {
            int2 q0 = epk[p], q1 = epk[p + 1], q2 = epk[p + 2], q3 = epk[p + 3];
            uint32 v0 = xwu[(size_t)q0.x * 64 + lane];
            uint32 v1 = xwu[(size_t)q1.x * 64 + lane];
            uint32 v2 = xwu[(size_t)q2.x * 64 + lane];
            uint32 v3 = xwu[(size_t)q3.x * 64 + lane];
            float w0 = __int_as_float(q0.y) * dinv[q0.x];
            float w1 = __int_as_float(q1.y) * dinv[q1.x];
            float w2 = __int_as_float(q2.y) * dinv[q2.x];
            float w3 = __int_as_float(q3.y) * dinv[q3.x];
            ax += w0 * blo(v0) + w1 * blo(v1) + w2 * blo(v2) + w3 * blo(v3);
            ay += w0 * bhi(v0) + w1 * bhi(v1) + w2 * bhi(v2) + w3 * bhi(v3);
        }
        uint32 pk = packbf(ax, ay);
        aggu[(size_t)n * 64 + lane] = pk;
        float v0 = blo(pk), v1 = bhi(pk);
        s0 += v0; ss0 += v0 * v0; s1 += v1; ss1 += v1 * v1;
    }
    float* st2 = stats2r + (b & 7) * 256;
    sh[t] = s0; __syncthreads();
    if (t < 64) atomicAdd(&st2[2 * t], sh[t] + sh[t + 64] + sh[t + 128] + sh[t + 192]);
    __syncthreads(); sh[t] = s1; __syncthreads();
    if (t < 64) atomicAdd(&st2[2 * t + 1], sh[t] + sh[t + 64] + sh[t + 128] + sh[t + 192]);
    __syncthreads(); sh[t] = ss0; __syncthreads();
    if (t < 64) atomicAdd(&st2[128 + 2 * t], sh[t] + sh[t + 64] + sh[t + 128] + sh[t + 192]);
    __syncthreads(); sh[t] = ss1; __syncthreads();
    if (t < 64) atomicAdd(&st2[128 + 2 * t + 1], sh[t] + sh[t + 64] + sh[t + 128] + sh[t + 192]);
}

// ---------------------------------------------------------------------------
// 6) Fused pool + gemm2: block g computes pooled row g (LDS only), then
//    z1 row g = pooled_g @ W2^T.
// ---------------------------------------------------------------------------
__global__ __launch_bounds__(512) void k_poolg2(
    const uint32* __restrict__ aggu, const float* __restrict__ stats2r,
    const float* __restrict__ g2, const float* __restrict__ bb2,
    const float* __restrict__ w2, float* __restrict__ z1)
{
    __shared__ float sc[128], sf[128], sh[512], prow[128];
    int t = threadIdx.x, g = blockIdx.x;
    if (t < 128) {
        float su = 0.f, sq = 0.f;
        #pragma unroll
        for (int r = 0; r < 8; r++) {
            su += stats2r[r * 256 + t];
            sq += stats2r[r * 256 + 128 + t];
        }
        float mu  = su * (1.0f / N_NODES);
        float var = sq * (1.0f / N_NODES) - mu * mu;
        float rs  = rsqrtf(fmaxf(var, 0.f) + BN_EPS);
        float s   = rs * g2[t];
        sc[t] = s;
        sf[t] = bb2[t] - mu * s;
    }
    __syncthreads();
    int c = t & 63, grp = t >> 6;                 // 8 groups x 32 rows
    float c0s = sc[2 * c], c0f = sf[2 * c], c1s = sc[2 * c + 1], c1f = sf[2 * c + 1];
    const uint32* base = aggu + (size_t)g * 256 * 64;
    float s0 = 0.f, s1 = 0.f;
    for (int r = grp * 32; r < grp * 32 + 32; r++) {
        uint32 u = base[r * 64 + c];
        s0 += ftanh(blo(u) * c0s + c0f);
        s1 += ftanh(bhi(u) * c1s + c1f);
    }
    sh[t] = s0; __syncthreads();
    if (t < 64) {
        float acc = 0.f;
        #pragma unroll
        for (int k = 0; k < 8; k++) acc += sh[t + 64 * k];
        prow[2 * t] = acc * (1.0f / 256.0f);
    }
    __syncthreads(); sh[t] = s1; __syncthreads();
    if (t < 64) {
        float acc = 0.f;
        #pragma unroll
        for (int k = 0; k < 8; k++) acc += sh[t + 64 * k];
        prow[2 * t + 1] = acc * (1.0f / 256.0f);
    }
    __syncthreads();
    // ---- gemm2: z1[g][t] = sum_k prow[k] * w2[t][k], t < 256 ----
    if (t < 256) {
        float acc = 0.f;
        const float* wr = w2 + t * 128;
        for (int k = 0; k < 128; k++) acc += prow[k] * wr[k];
        z1[g * 256 + t] = acc;
    }
}

// y1 + fused BN3 stats into 8-way replicated accumulators
__global__ void k_dgcn1(const float* __restrict__ scen, const float* __restrict__ fcol,
                        const float* __restrict__ z1, const float* __restrict__ b2c,
                        float* __restrict__ y1, float* __restrict__ stats3r)
{
    __shared__ float wk[256];
    int i = blockIdx.x, t = threadIdx.x;
    float a = (scen[t * 256 + i] >= THRE) ? 1.0f : 0.0f;
    if (t == i) a += 1.0f;
    wk[t] = a * rsqrtf(fcol[t] + 1.0f);
    __syncthreads();
    float acc = 0.f;
    for (int k = 0; k < 256; k++) acc += wk[k] * z1[k * 256 + t];
    float v = rsqrtf(fcol[i] + 1.0f) * acc + b2c[t];
    y1[i * 256 + t] = v;
    float* s3 = stats3r + (i & 7) * 512;
    atomicAdd(&s3[t], v);
    atomicAdd(&s3[256 + t], v * v);
}

// z2 = tanh(BN3(y1)) @ W3^T. 256 threads: thread t computes output col t&127
// over k-half t>>7 (halved dependent chain, 2x waves), LDS pair-reduce.
__global__ __launch_bounds__(256) void k_gemm3(
    const float* __restrict__ y1, const float* __restrict__ stats3r,
    const float* __restrict__ g3, const float* __restrict__ bb3,
    const float* __restrict__ w3, float* __restrict__ z2)
{
    __shared__ float row[256];
    __shared__ float psum[256];
    int i = blockIdx.x, t = threadIdx.x;   // 256 blocks x 256
    {
        float s = 0.f, ss = 0.f;
        #pragma unroll
        for (int r = 0; r < 8; r++) {
            s  += stats3r[r * 512 + t];
            ss += stats3r[r * 512 + 256 + t];
        }
        float mu  = s * (1.0f / 256.0f);
        float var = ss * (1.0f / 256.0f) - mu * mu;
        float rs  = rsqrtf(fmaxf(var, 0.f) + BN_EPS);
        float scj = rs * g3[t];
        float sfj = bb3[t] - mu * scj;
        row[t] = ftanh(y1[i * 256 + t] * scj + sfj);
    }
    __syncthreads();
    int c = t & 127, h = t >> 7;
    const float* wr = w3 + c * 256 + h * 128;
    const float* rr = row + h * 128;
    float acc = 0.f;
    for (int k = 0; k < 128; k++) acc += rr[k] * wr[k];
    psum[t] = acc;
    __syncthreads();
    if (t < 128) z2[i * 128 + t] = psum[t] + psum[t + 128];
}

// feat = tanh(dense GCN(z2)) -> out rows; mean via 8-way replicas; last
// finishing block folds replicas. 256 threads: col t&127, k-half t>>7.
__global__ __launch_bounds__(256) void k_dgcn2(
    const float* __restrict__ scen, const float* __restrict__ fcol,
    const float* __restrict__ z2, const float* __restrict__ b3c,
    float* __restrict__ out, float* __restrict__ meanr,
    int* __restrict__ ctr)
{
    __shared__ float wk[256];
    __shared__ float psum[256];
    __shared__ int flag;
    int i = blockIdx.x, t = threadIdx.x;   // 256 blocks x 256
    {
        float a = (scen[t * 256 + i] >= THRE) ? 1.0f : 0.0f;
        if (t == i) a += 1.0f;
        wk[t] = a * rsqrtf(fcol[t] + 1.0f);
    }
    __syncthreads();
    int c = t & 127, h = t >> 7;
    const float* wkh = wk + h * 128;
    const float* zc  = z2 + (size_t)h * 128 * 128 + c;
    float acc = 0.f;
    for (int k = 0; k < 128; k++) acc += wkh[k] * zc[k * 128];
    psum[t] = acc;
    __syncthreads();
    if (t < 128) {
        float v = ftanh(rsqrtf(fcol[i] + 1.0f) * (psum[t] + psum[t + 128]) + b3c[t]);
        out[i * 128 + t] = v;
        atomicAdd(&meanr[(i & 7) * 128 + t], v);
    }
    __syncthreads();
    if (t == 0) {
        __threadfence();
        flag = (atomicAdd(ctr, 1) == 255) ? 1 : 0;
    }
    __syncthreads();
    if (flag) {
        __threadfence();
        if (t < 128) {
            float s = 0.f;
            #pragma unroll
            for (int r = 0; r < 8; r++) s += meanr[r * 128 + t];
            out[S_GRAPH * 128 + t] = s * (1.0f / 256.0f);
        }
    }
}

// ---------------------------------------------------------------------------
extern "C" void kernel_launch(void* const* d_in, const int* in_sizes, int n_in,
                              void* d_out, int out_size, void* d_ws, size_t ws_size,
                              hipStream_t stream)
{
    const float* x        = (const float*)d_in[0];
    const float* edge_attr= (const float*)d_in[1];
    const float* scen     = (const float*)d_in[2];
    const float* wv       = (const float*)d_in[3];
    const float* bv       = (const float*)d_in[4];
    const float* wc       = (const float*)d_in[5];
    const float* bc       = (const float*)d_in[6];
    const float* w1       = (const float*)d_in[7];
    const float* b1c      = (const float*)d_in[8];
    const float* w2       = (const float*)d_in[9];
    const float* b2c      = (const float*)d_in[10];
    const float* w3       = (const float*)d_in[11];
    const float* b3c      = (const float*)d_in[12];
    const float* g1       = (const float*)d_in[13];
    const float* bb1      = (const float*)d_in[14];
    const float* g2       = (const float*)d_in[15];
    const float* bb2      = (const float*)d_in[16];
    const float* g3       = (const float*)d_in[17];
    const float* bb3      = (const float*)d_in[18];
    const int*  ei        = (const int*)d_in[20];
    const int*  nconp     = (const int*)d_in[22];
    const int*  src = ei;
    const int*  dst = ei + N_EDGES;

    float* wsf = (float*)d_ws;
    uint32*   h0u  = (uint32*)wsf;            // 16.7MB, dead after gemm1
    uint32*   aggu = (uint32*)wsf;            // alias
    uint32*   xwu  = (uint32*)(wsf + 4194304);// 16.7MB
    float* zb      = wsf + 8388608;
    float* stats1  = zb;                      // 256 (non-atomic, from pstat)
    float* zacc    = zb + 512;                // stats2r(2048)+stats3r(4096)+meanr(1024)
    float* stats2r = zacc;                    // 2048
    float* stats3r = zacc + 2048;             // 4096
    float* meanr   = zacc + 6144;             // 1024
    float* fcol    = zb + 7680;               // 256 (non-atomic)
    int*   ctrs    = (int*)(zb + 7936);       // 8 counters (zeroed in k_mlp_hist)
    float* deg     = zb + 7944;               // 65536 (dinv)
    int*   rowp    = (int*)(deg + 65536);     // 65536 (absolute padded offsets)
    int*   cnts    = rowp + 65536;            // 65536
    uint32* blkhist= (uint32*)(cnts + 65536); // 512*256 [block][bin]
    uint32* blkoff = blkhist + 131072;        // 256*512 [bin][block]
    uint32* binsz  = blkoff + 131072;         // 256
    uint32* ubase  = binsz + 256;             // 256
    uint32* pbase  = ubase + 256;             // 256
    uint2* ebin    = (uint2*)(pbase + 256);   // 524288 uint2 (binned edges)
    int2*  epk     = (int2*)(ebin + 524288);  // 720896 int2 (padded CSR)
    uint32* w1bk   = (uint32*)(epk + 720896); // 8192 (32KB bf16 W1)
    float* z1      = (float*)(w1bk + 8192);   // 65536
    float* y1      = z1 + 65536;              // 65536
    float* z2      = y1 + 65536;              // 32768
    float* pstat   = z2 + 32768;              // 512*256 stats1 partials

    float* out = (float*)d_out;

    k_mlp_hist<<<1057, 256, 0, stream>>>(x, wv, bv, wc, bc, nconp, h0u, pstat,
                                         dst, blkhist, scen, fcol, w1, w1bk,
                                         zacc, ctrs);
    k_binscan<<<257, 256, 0, stream>>>(blkhist, blkoff, binsz, ubase, pbase,
                                       pstat, stats1, &ctrs[0]);
    k_sg<<<1536, 256, 0, stream>>>(src, dst, edge_attr, blkoff, ubase, ebin,
                                   h0u, w1bk, g1, bb1, stats1, (ushort16*)xwu);
    k_csr<<<256, 256, 0, stream>>>(ebin, binsz, ubase, pbase, deg, rowp, cnts, epk);
    k_gather<<<2048, 256, 0, stream>>>(rowp, cnts, epk, xwu, deg,
                                       (const float2*)b1c, aggu, stats2r);
    k_poolg2<<<S_GRAPH, 512, 0, stream>>>(aggu, stats2r, g2, bb2, w2, z1);
    k_dgcn1<<<256, 256, 0, stream>>>(scen, fcol, z1, b2c, y1, stats3r);
    k_gemm3<<<256, 256, 0, stream>>>(y1, stats3r, g3, bb3, w3, z2);
    k_dgcn2<<<256, 256, 0, stream>>>(scen, fcol, z2, b3c, out, meanr, &ctrs[1]);
}